// Round 14
// baseline (971.658 us; speedup 1.0000x reference)
//
#include <hip/hip_runtime.h>

#define NCC 200000
#define NPRR 100000
#define NEE 500000
#define NBB 200000

typedef __attribute__((ext_vector_type(8))) short bf16x8;
typedef __attribute__((ext_vector_type(16))) float f32x16;

__device__ __forceinline__ float b2f(unsigned short u){ return __uint_as_float(((unsigned)u)<<16); }
__device__ __forceinline__ unsigned short f2b(float f){
  unsigned x = __float_as_uint(f);
  return (unsigned short)((x + 0x7fffu + ((x>>16)&1u)) >> 16);
}
// async global->LDS DMA, 16B/lane; LDS dest = uniform base + lane*16 (HW)
__device__ __forceinline__ void gl2lds16(const void* g, void* l){
  __builtin_amdgcn_global_load_lds(
      (const __attribute__((address_space(1))) unsigned int*)g,
      (__attribute__((address_space(3))) unsigned int*)l, 16, 0, 0);
}

// ---- WA prep (both node types in one launch): WA[set][k][h] ----
__global__ __launch_bounds__(256) void wa_prep2(
    const float* __restrict__ Wc, const float* __restrict__ bc,
    const float* __restrict__ attAc, const float* __restrict__ attBc,
    const float* __restrict__ Wp, const float* __restrict__ bp,
    const float* __restrict__ attAp, const float* __restrict__ attBp,
    float* __restrict__ WAc, float* __restrict__ WAp)
{
  int tid = threadIdx.x;
  for (int task = tid; task < 4*17*8; task += 256) {
    int grp = task / 136, rem = task % 136;
    int k = rem >> 3, h = rem & 7;
    const float* att = (grp==0)?attAc:(grp==1)?attBc:(grp==2)?attAp:attBp;
    const float* W   = (grp<2)?Wc:Wp;
    const float* bias= (grp<2)?bc:bp;
    const float* row = (k < 16) ? (W + k*256) : bias;
    float acc = 0.f;
    for (int d = 0; d < 32; d++) acc = fmaf(row[h*32+d], att[h*32+d], acc);
    if (grp<2) WAc[(grp&1)*136 + rem] = acc;
    else       WAp[(grp&1)*136 + rem] = acc;
  }
}

// ---- prep for restructured fc1: Bt_c/Bt_p (W1 halves, transposed bf16) + emb tables ----
// Ts[s][j] = b1[j] + sum_c size_emb[s][c]*W1[512+c][j]; Tc, Tg likewise (no bias)
__global__ __launch_bounds__(256) void prep_fc1(const float* __restrict__ fc1W,
    const float* __restrict__ fc1b,
    const float* __restrict__ size_emb, const float* __restrict__ color_emb,
    const float* __restrict__ group_emb,
    unsigned short* __restrict__ BtC, unsigned short* __restrict__ BtP,
    float* __restrict__ Ts, float* __restrict__ Tc, float* __restrict__ Tg)
{
  int idx = blockIdx.x*256 + threadIdx.x;
  if (idx < 32768){                       // BtC[n][k] = W1[k][n], k<256
    int n = idx>>8, k = idx&255;
    BtC[idx] = f2b(fc1W[k*128 + n]);
  } else if (idx < 65536){                // BtP[n][k] = W1[256+k][n]
    int t = idx - 32768;
    int n = t>>8, k = t&255;
    BtP[t] = f2b(fc1W[(256+k)*128 + n]);
  } else if (idx < 65536 + 30*128){       // Ts (bias folded)
    int t = idx - 65536;
    int s = t>>7, j = t&127;
    float a = fc1b[j];
    #pragma unroll
    for (int c=0;c<4;c++) a = fmaf(size_emb[s*4+c], fc1W[(512+c)*128+j], a);
    Ts[t] = a;
  } else if (idx < 65536 + 30*128 + 1000*128){  // Tc
    int t = idx - 65536 - 30*128;
    int col = t>>7, j = t&127;
    float a = 0.f;
    #pragma unroll
    for (int c=0;c<8;c++) a = fmaf(color_emb[col*8+c], fc1W[(516+c)*128+j], a);
    Tc[t] = a;
  } else if (idx < 65536 + 30*128 + 1000*128 + 50*128){  // Tg
    int t = idx - 65536 - 30*128 - 1000*128;
    int g = t>>7, j = t&127;
    float a = 0.f;
    #pragma unroll
    for (int c=0;c<4;c++) a = fmaf(group_emb[g*4+c], fc1W[(524+c)*128+j], a);
    Tg[t] = a;
  }
}

// ---- projection + fused scores: H=X@W+b (bf16), sA/sB = x·(W@att)+b·att ----
__global__ __launch_bounds__(256) void proj_kernel(const float* __restrict__ X,
    const float* __restrict__ W, const float* __restrict__ b,
    const float* __restrict__ WA,
    unsigned short* __restrict__ H, float* __restrict__ sA, float* __restrict__ sB, int N)
{
  __shared__ float Wl[16*256];
  __shared__ float bl[256];
  __shared__ float xs[8*16];
  __shared__ float wa[272];
  int tid = threadIdx.x;
  #pragma unroll
  for (int i=0;i<16;i++) Wl[i*256+tid] = W[i*256+tid];
  bl[tid] = b[tid];
  for (int i=tid;i<272;i+=256) wa[i]=WA[i];
  int nh = tid>>7;
  int c2 = (tid&127)*2;
  for (int base = blockIdx.x*8; base < N; base += gridDim.x*8) {
    __syncthreads();
    if (tid < 128) {
      int n = tid>>4, k = tid&15;
      int node = base + n;
      xs[tid] = (node < N) ? X[(long long)node*16+k] : 0.f;
    }
    __syncthreads();
    if (tid < 128){
      int nn = tid>>4, t = tid&15;
      int set = t>>3, h = t&7;
      int node = base + nn;
      if (node < N){
        const float* w = wa + set*136;
        float a = w[128 + h];
        #pragma unroll
        for (int k=0;k<16;k++) a = fmaf(xs[nn*16+k], w[k*8+h], a);
        (set ? sB : sA)[(long long)node*8 + h] = a;
      }
    }
    #pragma unroll
    for (int np=0;np<4;np++){
      int n = np*2 + nh;
      int node = base+n;
      if (node < N){
        float a0 = bl[c2], a1 = bl[c2+1];
        #pragma unroll
        for (int k=0;k<16;k++){
          float xv = xs[n*16+k];
          a0 = fmaf(xv, Wl[k*256+c2],   a0);
          a1 = fmaf(xv, Wl[k*256+c2+1], a1);
        }
        *(unsigned*)&H[(long long)node*256 + c2] = (unsigned)f2b(a0) | ((unsigned)f2b(a1)<<16);
      }
    }
  }
}

// ---- fused degree histogram for both relations ----
__global__ __launch_bounds__(256) void hist2(const int* __restrict__ src, const int* __restrict__ dst,
    int* __restrict__ cnt_c, int* __restrict__ cnt_p, int E)
{
  int e = blockIdx.x*256 + threadIdx.x;
  if (e >= E) return;
  atomicAdd(&cnt_p[dst[e]], 1);
  atomicAdd(&cnt_c[src[e]], 1);
}

// ---- hierarchical exclusive scan ----
__global__ __launch_bounds__(256) void scan_phase1(const int* __restrict__ cnt, int* __restrict__ bsum, int N)
{
  __shared__ int red[256];
  int tid = threadIdx.x;
  int base = blockIdx.x*1024 + tid*4;
  int s = 0;
  #pragma unroll
  for (int k=0;k<4;k++){ int i=base+k; if (i<N) s += cnt[i]; }
  red[tid] = s;
  __syncthreads();
  for (int off=128; off>0; off>>=1){ if (tid<off) red[tid]+=red[tid+off]; __syncthreads(); }
  if (tid==0) bsum[blockIdx.x] = red[0];
}

__global__ __launch_bounds__(256) void scan_phase2(int* __restrict__ bsum, int B,
    int* __restrict__ rowptr, int N)
{
  __shared__ int ts[256];
  int tid = threadIdx.x;
  int v = (tid<B) ? bsum[tid] : 0;
  ts[tid] = v;
  __syncthreads();
  for (int off=1; off<256; off<<=1){
    int t = (tid>=off) ? ts[tid-off] : 0;
    __syncthreads();
    ts[tid] += t;
    __syncthreads();
  }
  if (tid < B) bsum[tid] = ts[tid] - v;
  if (tid == B-1) rowptr[N] = ts[tid];
}

__global__ __launch_bounds__(256) void scan_phase3(const int* __restrict__ cnt,
    const int* __restrict__ bsum, int* __restrict__ rowptr, int N)
{
  __shared__ int ts[256];
  int tid = threadIdx.x;
  int base = blockIdx.x*1024 + tid*4;
  int v[4]; int s = 0;
  #pragma unroll
  for (int k=0;k<4;k++){ int i=base+k; v[k] = (i<N) ? cnt[i] : 0; s += v[k]; }
  ts[tid] = s;
  __syncthreads();
  for (int off=1; off<256; off<<=1){
    int t = (tid>=off) ? ts[tid-off] : 0;
    __syncthreads();
    ts[tid] += t;
    __syncthreads();
  }
  int run = bsum[blockIdx.x] + ts[tid] - s;
  #pragma unroll
  for (int k=0;k<4;k++){ int i=base+k; if (i<N){ rowptr[i]=run; run += v[k]; } }
}

// ---- fused placement for both relations (uses pre-zeroed cnt2 buffers) ----
__global__ __launch_bounds__(256) void place2(const int* __restrict__ src, const int* __restrict__ dst,
    const int* __restrict__ rp_r, const int* __restrict__ rp_rb,
    int* __restrict__ cnt_p, int* __restrict__ cnt_c,
    int* __restrict__ si_r, int* __restrict__ si_rb, int E)
{
  int e = blockIdx.x*256 + threadIdx.x;
  if (e >= E) return;
  int s = src[e], d = dst[e];
  si_r [rp_r [d] + atomicAdd(&cnt_p[d], 1)] = s;
  si_rb[rp_rb[s] + atomicAdd(&cnt_c[s], 1)] = d;
}

// ---- aggregation v2: lanes split (side, colgroup); uint4 row loads; single pass ----
__global__ __launch_bounds__(256) void agg_kernel(
    const int* __restrict__ rowptr, const int* __restrict__ srcidx,
    const float* __restrict__ sSrc, const float* __restrict__ sDst,
    const unsigned short* __restrict__ H, unsigned short* __restrict__ out, int N)
{
  int wv = threadIdx.x >> 6, lane = threadIdx.x & 63;
  int n = blockIdx.x*4 + wv;
  if (n >= N) return;
  int e0 = rowptr[n], e1 = rowptr[n+1];
  int j = lane & 31;
  int side = lane >> 5;
  int h = j >> 2;
  float sdh = sDst[(long long)n*8 + h];
  float a0=0,a1=0,a2=0,a3=0,a4=0,a5=0,a6=0,a7=0, da=0.f;
  float b0=0,b1=0,b2=0,b3=0,b4=0,b5=0,b6=0,b7=0, db=0.f;
  int e = e0 + side;
  for (; e + 2 < e1; e += 4){
    int sA = srcidx[e], sB = srcidx[e+2];
    float lA = sSrc[(long long)sA*8 + h] + sdh;
    float lB = sSrc[(long long)sB*8 + h] + sdh;
    uint4 uA = *(const uint4*)&H[(long long)sA*256 + j*8];
    uint4 uB = *(const uint4*)&H[(long long)sB*256 + j*8];
    float wA = __expf(lA > 0.f ? lA : 0.2f*lA);
    float wB = __expf(lB > 0.f ? lB : 0.2f*lB);
    da += wA; db += wB;
    a0 = fmaf(wA, b2f((unsigned short)(uA.x&0xffffu)), a0);
    a1 = fmaf(wA, b2f((unsigned short)(uA.x>>16)),     a1);
    a2 = fmaf(wA, b2f((unsigned short)(uA.y&0xffffu)), a2);
    a3 = fmaf(wA, b2f((unsigned short)(uA.y>>16)),     a3);
    a4 = fmaf(wA, b2f((unsigned short)(uA.z&0xffffu)), a4);
    a5 = fmaf(wA, b2f((unsigned short)(uA.z>>16)),     a5);
    a6 = fmaf(wA, b2f((unsigned short)(uA.w&0xffffu)), a6);
    a7 = fmaf(wA, b2f((unsigned short)(uA.w>>16)),     a7);
    b0 = fmaf(wB, b2f((unsigned short)(uB.x&0xffffu)), b0);
    b1 = fmaf(wB, b2f((unsigned short)(uB.x>>16)),     b1);
    b2 = fmaf(wB, b2f((unsigned short)(uB.y&0xffffu)), b2);
    b3 = fmaf(wB, b2f((unsigned short)(uB.y>>16)),     b3);
    b4 = fmaf(wB, b2f((unsigned short)(uB.z&0xffffu)), b4);
    b5 = fmaf(wB, b2f((unsigned short)(uB.z>>16)),     b5);
    b6 = fmaf(wB, b2f((unsigned short)(uB.w&0xffffu)), b6);
    b7 = fmaf(wB, b2f((unsigned short)(uB.w>>16)),     b7);
  }
  for (; e < e1; e += 2){
    int s = srcidx[e];
    float l = sSrc[(long long)s*8 + h] + sdh;
    uint4 u = *(const uint4*)&H[(long long)s*256 + j*8];
    float w = __expf(l > 0.f ? l : 0.2f*l);
    da += w;
    a0 = fmaf(w, b2f((unsigned short)(u.x&0xffffu)), a0);
    a1 = fmaf(w, b2f((unsigned short)(u.x>>16)),     a1);
    a2 = fmaf(w, b2f((unsigned short)(u.y&0xffffu)), a2);
    a3 = fmaf(w, b2f((unsigned short)(u.y>>16)),     a3);
    a4 = fmaf(w, b2f((unsigned short)(u.z&0xffffu)), a4);
    a5 = fmaf(w, b2f((unsigned short)(u.z>>16)),     a5);
    a6 = fmaf(w, b2f((unsigned short)(u.w&0xffffu)), a6);
    a7 = fmaf(w, b2f((unsigned short)(u.w>>16)),     a7);
  }
  a0+=b0; a1+=b1; a2+=b2; a3+=b3; a4+=b4; a5+=b5; a6+=b6; a7+=b7;
  da += db;
  a0 += __shfl_xor(a0,32); a1 += __shfl_xor(a1,32);
  a2 += __shfl_xor(a2,32); a3 += __shfl_xor(a3,32);
  a4 += __shfl_xor(a4,32); a5 += __shfl_xor(a5,32);
  a6 += __shfl_xor(a6,32); a7 += __shfl_xor(a7,32);
  da += __shfl_xor(da,32);
  float inv = 1.f/(da + 1e-16f);
  if (side == 0){
    uint4 o;
    o.x = (unsigned)f2b(fmaxf(a0*inv,0.f)) | ((unsigned)f2b(fmaxf(a1*inv,0.f))<<16);
    o.y = (unsigned)f2b(fmaxf(a2*inv,0.f)) | ((unsigned)f2b(fmaxf(a3*inv,0.f))<<16);
    o.z = (unsigned)f2b(fmaxf(a4*inv,0.f)) | ((unsigned)f2b(fmaxf(a5*inv,0.f))<<16);
    o.w = (unsigned)f2b(fmaxf(a6*inv,0.f)) | ((unsigned)f2b(fmaxf(a7*inv,0.f))<<16);
    *(uint4*)&out[(long long)n*256 + j*8] = o;
  }
}

// ---- dense streaming GEMM: Y[M][128] = A[M][256] @ Bt^T (both bf16, fp32 acc) ----
__global__ __launch_bounds__(256) void gemmY(const unsigned short* __restrict__ A,
    const unsigned short* __restrict__ Bt, unsigned short* __restrict__ Y, int M)
{
  __shared__ unsigned short feat[32*264];   // row stride 264 (528B, 16B-aligned)
  int tid = threadIdx.x;
  int wv = tid>>6, lane = tid&63;
  long long base = (long long)blockIdx.x*32;
  #pragma unroll
  for (int i=0;i<8;i++){
    int r = wv*8 + i;
    if (lane < 32) gl2lds16(A + (base+r)*256 + lane*8, &feat[r*264]);
  }
  __syncthreads();
  int m = lane&31, hi = lane>>5;
  f32x16 acc;
  #pragma unroll
  for (int i=0;i<16;i++) acc[i]=0.f;
  const unsigned short* ap  = feat + m*264 + hi*8;
  const unsigned short* btp = Bt + (wv*32 + m)*256 + hi*8;
  #pragma unroll 4
  for (int ks=0; ks<16; ks++){
    bf16x8 a = *(const bf16x8*)(ap + ks*16);
    bf16x8 b = *(const bf16x8*)(btp + ks*16);
    acc = __builtin_amdgcn_mfma_f32_32x32x16_bf16(a, b, acc, 0, 0, 0);
  }
  int col = wv*32 + m;
  #pragma unroll
  for (int reg=0; reg<16; reg++){
    int row = (reg&3) + 8*(reg>>2) + 4*hi;
    Y[(base+row)*128 + col] = f2b(acc[reg]);
  }
}

// ---- gather + sum + relu + BN1 stats: x1 = relu(Yc[ls]+Yp[ld]+Ts[si]+Tc[ci]+Tg[gi]) ----
__global__ __launch_bounds__(256) void gather_fc1(
    const unsigned short* __restrict__ Yc, const unsigned short* __restrict__ Yp,
    const float* __restrict__ Ts, const float* __restrict__ Tc, const float* __restrict__ Tg,
    const int* __restrict__ lsrc, const int* __restrict__ ldst,
    const int* __restrict__ sidx, const int* __restrict__ cidx, const int* __restrict__ gidx,
    unsigned short* __restrict__ x1, float* __restrict__ bnsum)
{
  __shared__ float redS[16][128];
  __shared__ float redQ[16][128];
  int tid = threadIdx.x;
  int rl = tid>>4, g = tid&15;             // 16 rows x 16 col-groups of 8
  long long row = (long long)blockIdx.x*16 + rl;
  int ls = lsrc[row], ld = ldst[row], si = sidx[row], ci = cidx[row], gi = gidx[row];
  uint4 uc = *(const uint4*)&Yc[(long long)ls*128 + g*8];
  uint4 up = *(const uint4*)&Yp[(long long)ld*128 + g*8];
  float4 t0 = *(const float4*)&Ts[si*128 + g*8];
  float4 t1 = *(const float4*)&Ts[si*128 + g*8 + 4];
  float4 c0 = *(const float4*)&Tc[ci*128 + g*8];
  float4 c1 = *(const float4*)&Tc[ci*128 + g*8 + 4];
  float4 g0 = *(const float4*)&Tg[gi*128 + g*8];
  float4 g1 = *(const float4*)&Tg[gi*128 + g*8 + 4];
  unsigned ucs[4] = {uc.x,uc.y,uc.z,uc.w};
  unsigned ups[4] = {up.x,up.y,up.z,up.w};
  float tb[8] = {t0.x+c0.x+g0.x, t0.y+c0.y+g0.y, t0.z+c0.z+g0.z, t0.w+c0.w+g0.w,
                 t1.x+c1.x+g1.x, t1.y+c1.y+g1.y, t1.z+c1.z+g1.z, t1.w+c1.w+g1.w};
  unsigned short ov[8];
  #pragma unroll
  for (int p=0;p<4;p++){
    float vl = b2f((unsigned short)(ucs[p]&0xffffu)) + b2f((unsigned short)(ups[p]&0xffffu)) + tb[p*2];
    float vh = b2f((unsigned short)(ucs[p]>>16))     + b2f((unsigned short)(ups[p]>>16))     + tb[p*2+1];
    vl = fmaxf(vl, 0.f); vh = fmaxf(vh, 0.f);
    ov[p*2] = f2b(vl); ov[p*2+1] = f2b(vh);
    redS[rl][g*8+p*2]   = vl;  redQ[rl][g*8+p*2]   = vl*vl;   // per-row slot, reduced below
    redS[rl][g*8+p*2+1] = vh;  redQ[rl][g*8+p*2+1] = vh*vh;
  }
  *(uint4*)&x1[row*128 + g*8] = *(uint4*)ov;
  __syncthreads();
  if (tid < 128){
    float s=0.f, q=0.f;
    #pragma unroll
    for (int r=0;r<16;r++){ s += redS[r][tid]; q += redQ[r][tid]; }
    atomicAdd(&bnsum[tid], s);
    atomicAdd(&bnsum[128+tid], q);
  }
}

// ---- T2: fold BN1 into fc2 ----
__global__ void bn1_fold(const float* __restrict__ bnsum,
    const float* __restrict__ gamma, const float* __restrict__ beta,
    const float* __restrict__ fc2W, const float* __restrict__ fc2b,
    float* __restrict__ fc2p, float* __restrict__ b2p, float invB)
{
  __shared__ float sc[128], sh[128];
  int tid = threadIdx.x;
  if (tid<128){
    float mu  = bnsum[tid]*invB;
    float var = bnsum[128+tid]*invB - mu*mu;
    float s = gamma[tid] * rsqrtf(var + 1e-5f);
    sc[tid]=s; sh[tid]= beta[tid] - mu*s;
  }
  __syncthreads();
  for (int idx=tid; idx<128*32; idx+=256){ int k=idx>>5; fc2p[idx] = sc[k]*fc2W[idx]; }
  if (tid<32){
    float a = fc2b[tid];
    for (int k=0;k<128;k++) a = fmaf(sh[k], fc2W[k*32+tid], a);
    b2p[tid]=a;
  }
}

// ---- T3: x2 = relu(x1 @ fc2' + b2') bf16, BN2 stats ----
__global__ __launch_bounds__(256) void fc2_kernel(const unsigned short* __restrict__ x1,
    const float* __restrict__ fc2p, const float* __restrict__ b2p,
    unsigned short* __restrict__ x2, float* __restrict__ bnsum2)
{
  __shared__ float xt[64*128];
  __shared__ float Wl[128*32];
  __shared__ float redS[8][32];
  __shared__ float redQ[8][32];
  int tid = threadIdx.x;
  for (int idx=tid; idx<4096; idx+=256) Wl[idx]=fc2p[idx];
  long long base = (long long)blockIdx.x*64;
  const unsigned* x1u = (const unsigned*)x1;
  for (int idx=tid; idx<64*64; idx+=256){
    unsigned u = x1u[base*64 + idx];
    xt[idx*2]   = b2f((unsigned short)(u&0xffffu));
    xt[idx*2+1] = b2f((unsigned short)(u>>16));
  }
  __syncthreads();
  int tx=tid&31, ty=tid>>5;
  float acc[8];
  float bb=b2p[tx];
  #pragma unroll
  for (int i=0;i<8;i++) acc[i]=bb;
  for (int k=0;k<128;k++){
    float w=Wl[k*32+tx];
    #pragma unroll
    for (int i=0;i<8;i++) acc[i]=fmaf(xt[(ty*8+i)*128+k], w, acc[i]);
  }
  float s=0,q=0;
  #pragma unroll
  for (int i=0;i<8;i++){
    float v=fmaxf(acc[i],0.f);
    x2[(base+ty*8+i)*32+tx]=f2b(v);
    s+=v; q+=v*v;
  }
  redS[ty][tx]=s; redQ[ty][tx]=q;
  __syncthreads();
  if (tid<32){
    float a=0,b=0;
    #pragma unroll
    for (int j=0;j<8;j++){ a+=redS[j][tid]; b+=redQ[j][tid]; }
    atomicAdd(&bnsum2[tid],a); atomicAdd(&bnsum2[32+tid],b);
  }
}

// ---- T4: fold BN2 into fc3 ----
__global__ void bn2_fold(const float* __restrict__ bnsum2,
    const float* __restrict__ gamma2, const float* __restrict__ beta2,
    const float* __restrict__ fc3W, const float* __restrict__ fc3b,
    float* __restrict__ w3p, float invB)
{
  __shared__ float sh3[32];
  int tid = threadIdx.x;
  if (tid<32){
    float mu  = bnsum2[tid]*invB;
    float var = bnsum2[32+tid]*invB - mu*mu;
    float s   = gamma2[tid] * rsqrtf(var + 1e-5f);
    float shv = beta2[tid] - mu*s;
    float w   = fc3W[tid];
    w3p[tid]  = s*w;
    sh3[tid]  = shv*w;
  }
  __syncthreads();
  if (tid==0){
    float a = fc3b[0];
    for (int j=0;j<32;j++) a += sh3[j];
    w3p[32] = a;
  }
}

// ---- T5: out = x2 @ w3' + b3' (fp32 out) ----
__global__ __launch_bounds__(256) void fc3_kernel(const unsigned short* __restrict__ x2,
    const float* __restrict__ w3p, float* __restrict__ out)
{
  __shared__ float wl[34];
  int tid = threadIdx.x;
  if (tid<33) wl[tid]=w3p[tid];
  __syncthreads();
  long long row = (long long)blockIdx.x*32 + (tid>>3);
  int j0 = (tid&7)*4;
  uint2 u = *(const uint2*)(x2 + row*32 + j0);
  float a = b2f((unsigned short)(u.x&0xffffu))*wl[j0]
          + b2f((unsigned short)(u.x>>16))   *wl[j0+1]
          + b2f((unsigned short)(u.y&0xffffu))*wl[j0+2]
          + b2f((unsigned short)(u.y>>16))   *wl[j0+3];
  a += __shfl_xor(a,1);
  a += __shfl_xor(a,2);
  a += __shfl_xor(a,4);
  if ((tid&7)==0) out[row] = a + wl[32];
}

extern "C" void kernel_launch(void* const* d_in, const int* in_sizes, int n_in,
                              void* d_out, int out_size, void* d_ws, size_t ws_size,
                              hipStream_t stream)
{
  (void)in_sizes; (void)n_in; (void)out_size; (void)ws_size;
  const float* customer_x = (const float*)d_in[0];
  const float* product_x  = (const float*)d_in[1];
  const float* pcW = (const float*)d_in[2];
  const float* pcB = (const float*)d_in[3];
  const float* ppW = (const float*)d_in[4];
  const float* ppB = (const float*)d_in[5];
  const float* att_src_r  = (const float*)d_in[6];
  const float* att_dst_r  = (const float*)d_in[7];
  const float* att_src_rb = (const float*)d_in[8];
  const float* att_dst_rb = (const float*)d_in[9];
  // d_in[10..12] dead (semantic softmax over 1 metapath == 1)
  const float* color_emb = (const float*)d_in[13];
  const float* size_emb  = (const float*)d_in[14];
  const float* group_emb = (const float*)d_in[15];
  const float* fc1W = (const float*)d_in[16];
  const float* fc1b = (const float*)d_in[17];
  const float* fc2W = (const float*)d_in[18];
  const float* fc2b = (const float*)d_in[19];
  const float* fc3W = (const float*)d_in[20];
  const float* fc3b = (const float*)d_in[21];
  const float* bn1g = (const float*)d_in[22];
  const float* bn1b = (const float*)d_in[23];
  const float* bn2g = (const float*)d_in[24];
  const float* bn2b = (const float*)d_in[25];
  const int* edge_src  = (const int*)d_in[26];
  const int* edge_dst  = (const int*)d_in[27];
  const int* label_src = (const int*)d_in[28];
  const int* label_dst = (const int*)d_in[29];
  const int* size_idx  = (const int*)d_in[30];
  const int* color_idx = (const int*)d_in[31];
  const int* group_idx = (const int*)d_in[32];

  char* ws = (char*)d_ws;
  size_t off = 0;
  auto alloc = [&](size_t bytes)->char* {
    char* p = ws + off;
    off += (bytes + 255) & ~(size_t)255;
    return p;
  };
  // ~236 MB peak (< 256 MiB hard limit)
  unsigned short* H_c  = (unsigned short*)alloc((size_t)NCC*256*2);   // 102.4 MB: H_c -> out_c -> x1
  unsigned short* H_p  = (unsigned short*)alloc((size_t)NPRR*256*2);  // 51.2 MB: H_p -> Y_p
  unsigned short* out_p= (unsigned short*)alloc((size_t)NPRR*256*2);  // 51.2 MB: out_p -> Y_c
  float* s_cr     = (float*)alloc((size_t)NCC*8*4);     // 6.4 MB (x2b aliases after aggs)
  float* s_crb    = (float*)alloc((size_t)NCC*8*4);     // 6.4 MB
  float* s_pr     = (float*)alloc((size_t)NPRR*8*4);    // 3.2 MB
  float* s_prb    = (float*)alloc((size_t)NPRR*8*4);    // 3.2 MB
  int* rowptr_r   = (int*)alloc((size_t)(NPRR+1)*4);
  int* rowptr_rb  = (int*)alloc((size_t)(NCC+1)*4);
  int* srcidx_r   = (int*)alloc((size_t)NEE*4);         // 2 MB
  int* srcidx_rb  = (int*)alloc((size_t)NEE*4);         // 2 MB
  int* cnts       = (int*)alloc((size_t)(NCC+NPRR)*2*4);
  int* cnt_c      = cnts;
  int* cnt_p      = cnts + NCC;
  int* cnt_c2     = cnts + NCC + NPRR;
  int* cnt_p2     = cnts + NCC + NPRR + NCC;
  int* bsum_c     = (int*)alloc(256*4);
  int* bsum_p     = (int*)alloc(256*4);
  unsigned short* BtC = (unsigned short*)alloc(128*256*2);
  unsigned short* BtP = (unsigned short*)alloc(128*256*2);
  float* Ts     = (float*)alloc(30*128*4);
  float* Tc     = (float*)alloc(1000*128*4);
  float* Tg     = (float*)alloc(50*128*4);
  float* wa_c   = (float*)alloc(272*4);
  float* wa_p   = (float*)alloc(272*4);
  float* bnsum1 = (float*)alloc(256*4);
  float* bnsum2 = (float*)alloc(64*4);
  float* fc2p   = (float*)alloc(4096*4);
  float* b2p    = (float*)alloc(32*4);
  float* w3p    = (float*)alloc(34*4);
  unsigned short* out_c = H_c;                   // H_c dead after agg_r
  unsigned short* Y_p   = H_p;                   // H_p dead after agg_rb
  unsigned short* Y_c   = out_p;                 // out_p dead after gemmY_p
  unsigned short* x1b   = H_c;                   // out_c dead after gemmY_c
  unsigned short* x2b   = (unsigned short*)s_cr; // scores dead after aggs

  hipMemsetAsync(bnsum1, 0, 1280, stream);       // bnsum1+bnsum2 contiguous
  hipMemsetAsync(cnts, 0, (size_t)(NCC+NPRR)*2*4, stream);

  // prep: WA (scores), fc1 restructure tables/weights
  wa_prep2<<<1,256,0,stream>>>(pcW, pcB, att_src_r, att_dst_rb,
                               ppW, ppB, att_dst_r, att_src_rb, wa_c, wa_p);
  prep_fc1<<<(203776+255)/256,256,0,stream>>>(fc1W, fc1b, size_emb, color_emb, group_emb,
      BtC, BtP, Ts, Tc, Tg);

  // proj + fused scores
  proj_kernel<<<2048,256,0,stream>>>(customer_x, pcW, pcB, wa_c, H_c, s_cr, s_crb, NCC);
  proj_kernel<<<2048,256,0,stream>>>(product_x,  ppW, ppB, wa_p, H_p, s_pr, s_prb, NPRR);

  // CSR build (both relations)
  const int eg = (NEE+255)/256;
  const int BP = (NPRR+1023)/1024;   // 98
  const int BC = (NCC +1023)/1024;   // 196
  hist2<<<eg,256,0,stream>>>(edge_src, edge_dst, cnt_c, cnt_p, NEE);
  scan_phase1<<<BP,256,0,stream>>>(cnt_p, bsum_p, NPRR);
  scan_phase2<<<1,256,0,stream>>>(bsum_p, BP, rowptr_r, NPRR);
  scan_phase3<<<BP,256,0,stream>>>(cnt_p, bsum_p, rowptr_r, NPRR);
  scan_phase1<<<BC,256,0,stream>>>(cnt_c, bsum_c, NCC);
  scan_phase2<<<1,256,0,stream>>>(bsum_c, BC, rowptr_rb, NCC);
  scan_phase3<<<BC,256,0,stream>>>(cnt_c, bsum_c, rowptr_rb, NCC);
  place2<<<eg,256,0,stream>>>(edge_src, edge_dst, rowptr_r, rowptr_rb,
      cnt_p2, cnt_c2, srcidx_r, srcidx_rb, NEE);

  // single-pass gather aggregation
  agg_kernel<<<(NPRR+3)/4,256,0,stream>>>(rowptr_r,  srcidx_r,  s_cr,  s_pr,  H_c, out_p, NPRR);
  agg_kernel<<<(NCC +3)/4,256,0,stream>>>(rowptr_rb, srcidx_rb, s_prb, s_crb, H_p, out_c, NCC);

  // restructured fc1: dense GEMMs (streaming, no gather) + light gather-add
  gemmY<<<NPRR/32,256,0,stream>>>(out_p, BtP, Y_p, NPRR);   // out_p consumed -> Y_c may overwrite
  gemmY<<<NCC/32,256,0,stream>>>(out_c, BtC, Y_c, NCC);     // out_c consumed -> x1 may overwrite
  gather_fc1<<<NBB/16,256,0,stream>>>(Y_c, Y_p, Ts, Tc, Tg,
      label_src, label_dst, size_idx, color_idx, group_idx, x1b, bnsum1);

  bn1_fold<<<1,256,0,stream>>>(bnsum1, bn1g, bn1b, fc2W, fc2b, fc2p, b2p, 1.0f/NBB);
  fc2_kernel<<<NBB/64,256,0,stream>>>(x1b, fc2p, b2p, x2b, bnsum2);
  bn2_fold<<<1,64,0,stream>>>(bnsum2, bn2g, bn2b, fc3W, fc3b, w3p, 1.0f/NBB);
  fc3_kernel<<<NBB/32,256,0,stream>>>(x2b, w3p, (float*)d_out);
}

// Round 15
// 737.189 us; speedup vs baseline: 1.3181x; 1.3181x over previous
//
#include <hip/hip_runtime.h>

#define NCC 200000
#define NPRR 100000
#define NEE 500000
#define NBB 200000

typedef __attribute__((ext_vector_type(8))) short bf16x8;
typedef __attribute__((ext_vector_type(16))) float f32x16;

__device__ __forceinline__ float b2f(unsigned short u){ return __uint_as_float(((unsigned)u)<<16); }
__device__ __forceinline__ unsigned short f2b(float f){
  unsigned x = __float_as_uint(f);
  return (unsigned short)((x + 0x7fffu + ((x>>16)&1u)) >> 16);
}
// async global->LDS DMA, 16B/lane; LDS dest = uniform base + lane*16 (HW)
__device__ __forceinline__ void gl2lds16(const void* g, void* l){
  __builtin_amdgcn_global_load_lds(
      (const __attribute__((address_space(1))) unsigned int*)g,
      (__attribute__((address_space(3))) unsigned int*)l, 16, 0, 0);
}

// ---- WA prep (both node types in one launch): WA[set][k][h] ----
__global__ __launch_bounds__(256) void wa_prep2(
    const float* __restrict__ Wc, const float* __restrict__ bc,
    const float* __restrict__ attAc, const float* __restrict__ attBc,
    const float* __restrict__ Wp, const float* __restrict__ bp,
    const float* __restrict__ attAp, const float* __restrict__ attBp,
    float* __restrict__ WAc, float* __restrict__ WAp)
{
  int tid = threadIdx.x;
  for (int task = tid; task < 4*17*8; task += 256) {
    int grp = task / 136, rem = task % 136;
    int k = rem >> 3, h = rem & 7;
    const float* att = (grp==0)?attAc:(grp==1)?attBc:(grp==2)?attAp:attBp;
    const float* W   = (grp<2)?Wc:Wp;
    const float* bias= (grp<2)?bc:bp;
    const float* row = (k < 16) ? (W + k*256) : bias;
    float acc = 0.f;
    for (int d = 0; d < 32; d++) acc = fmaf(row[h*32+d], att[h*32+d], acc);
    if (grp<2) WAc[(grp&1)*136 + rem] = acc;
    else       WAp[(grp&1)*136 + rem] = acc;
  }
}

// ---- prep for restructured fc1: Bt_c/Bt_p (W1 halves, transposed bf16) + emb tables ----
__global__ __launch_bounds__(256) void prep_fc1(const float* __restrict__ fc1W,
    const float* __restrict__ fc1b,
    const float* __restrict__ size_emb, const float* __restrict__ color_emb,
    const float* __restrict__ group_emb,
    unsigned short* __restrict__ BtC, unsigned short* __restrict__ BtP,
    float* __restrict__ Ts, float* __restrict__ Tc, float* __restrict__ Tg)
{
  int idx = blockIdx.x*256 + threadIdx.x;
  if (idx < 32768){                       // BtC[n][k] = W1[k][n], k<256
    int n = idx>>8, k = idx&255;
    BtC[idx] = f2b(fc1W[k*128 + n]);
  } else if (idx < 65536){                // BtP[n][k] = W1[256+k][n]
    int t = idx - 32768;
    int n = t>>8, k = t&255;
    BtP[t] = f2b(fc1W[(256+k)*128 + n]);
  } else if (idx < 65536 + 30*128){       // Ts (bias folded)
    int t = idx - 65536;
    int s = t>>7, j = t&127;
    float a = fc1b[j];
    #pragma unroll
    for (int c=0;c<4;c++) a = fmaf(size_emb[s*4+c], fc1W[(512+c)*128+j], a);
    Ts[t] = a;
  } else if (idx < 65536 + 30*128 + 1000*128){  // Tc
    int t = idx - 65536 - 30*128;
    int col = t>>7, j = t&127;
    float a = 0.f;
    #pragma unroll
    for (int c=0;c<8;c++) a = fmaf(color_emb[col*8+c], fc1W[(516+c)*128+j], a);
    Tc[t] = a;
  } else if (idx < 65536 + 30*128 + 1000*128 + 50*128){  // Tg
    int t = idx - 65536 - 30*128 - 1000*128;
    int g = t>>7, j = t&127;
    float a = 0.f;
    #pragma unroll
    for (int c=0;c<4;c++) a = fmaf(group_emb[g*4+c], fc1W[(524+c)*128+j], a);
    Tg[t] = a;
  }
}

// ---- projection + fused scores: H=X@W+b (bf16), sA/sB = x·(W@att)+b·att ----
__global__ __launch_bounds__(256) void proj_kernel(const float* __restrict__ X,
    const float* __restrict__ W, const float* __restrict__ b,
    const float* __restrict__ WA,
    unsigned short* __restrict__ H, float* __restrict__ sA, float* __restrict__ sB, int N)
{
  __shared__ float Wl[16*256];
  __shared__ float bl[256];
  __shared__ float xs[8*16];
  __shared__ float wa[272];
  int tid = threadIdx.x;
  #pragma unroll
  for (int i=0;i<16;i++) Wl[i*256+tid] = W[i*256+tid];
  bl[tid] = b[tid];
  for (int i=tid;i<272;i+=256) wa[i]=WA[i];
  int nh = tid>>7;
  int c2 = (tid&127)*2;
  for (int base = blockIdx.x*8; base < N; base += gridDim.x*8) {
    __syncthreads();
    if (tid < 128) {
      int n = tid>>4, k = tid&15;
      int node = base + n;
      xs[tid] = (node < N) ? X[(long long)node*16+k] : 0.f;
    }
    __syncthreads();
    if (tid < 128){
      int nn = tid>>4, t = tid&15;
      int set = t>>3, h = t&7;
      int node = base + nn;
      if (node < N){
        const float* w = wa + set*136;
        float a = w[128 + h];
        #pragma unroll
        for (int k=0;k<16;k++) a = fmaf(xs[nn*16+k], w[k*8+h], a);
        (set ? sB : sA)[(long long)node*8 + h] = a;
      }
    }
    #pragma unroll
    for (int np=0;np<4;np++){
      int n = np*2 + nh;
      int node = base+n;
      if (node < N){
        float a0 = bl[c2], a1 = bl[c2+1];
        #pragma unroll
        for (int k=0;k<16;k++){
          float xv = xs[n*16+k];
          a0 = fmaf(xv, Wl[k*256+c2],   a0);
          a1 = fmaf(xv, Wl[k*256+c2+1], a1);
        }
        *(unsigned*)&H[(long long)node*256 + c2] = (unsigned)f2b(a0) | ((unsigned)f2b(a1)<<16);
      }
    }
  }
}

// ---- fused degree histogram for both relations ----
__global__ __launch_bounds__(256) void hist2(const int* __restrict__ src, const int* __restrict__ dst,
    int* __restrict__ cnt_c, int* __restrict__ cnt_p, int E)
{
  int e = blockIdx.x*256 + threadIdx.x;
  if (e >= E) return;
  atomicAdd(&cnt_p[dst[e]], 1);
  atomicAdd(&cnt_c[src[e]], 1);
}

// ---- hierarchical exclusive scan ----
__global__ __launch_bounds__(256) void scan_phase1(const int* __restrict__ cnt, int* __restrict__ bsum, int N)
{
  __shared__ int red[256];
  int tid = threadIdx.x;
  int base = blockIdx.x*1024 + tid*4;
  int s = 0;
  #pragma unroll
  for (int k=0;k<4;k++){ int i=base+k; if (i<N) s += cnt[i]; }
  red[tid] = s;
  __syncthreads();
  for (int off=128; off>0; off>>=1){ if (tid<off) red[tid]+=red[tid+off]; __syncthreads(); }
  if (tid==0) bsum[blockIdx.x] = red[0];
}

__global__ __launch_bounds__(256) void scan_phase2(int* __restrict__ bsum, int B,
    int* __restrict__ rowptr, int N)
{
  __shared__ int ts[256];
  int tid = threadIdx.x;
  int v = (tid<B) ? bsum[tid] : 0;
  ts[tid] = v;
  __syncthreads();
  for (int off=1; off<256; off<<=1){
    int t = (tid>=off) ? ts[tid-off] : 0;
    __syncthreads();
    ts[tid] += t;
    __syncthreads();
  }
  if (tid < B) bsum[tid] = ts[tid] - v;
  if (tid == B-1) rowptr[N] = ts[tid];
}

__global__ __launch_bounds__(256) void scan_phase3(const int* __restrict__ cnt,
    const int* __restrict__ bsum, int* __restrict__ rowptr, int N)
{
  __shared__ int ts[256];
  int tid = threadIdx.x;
  int base = blockIdx.x*1024 + tid*4;
  int v[4]; int s = 0;
  #pragma unroll
  for (int k=0;k<4;k++){ int i=base+k; v[k] = (i<N) ? cnt[i] : 0; s += v[k]; }
  ts[tid] = s;
  __syncthreads();
  for (int off=1; off<256; off<<=1){
    int t = (tid>=off) ? ts[tid-off] : 0;
    __syncthreads();
    ts[tid] += t;
    __syncthreads();
  }
  int run = bsum[blockIdx.x] + ts[tid] - s;
  #pragma unroll
  for (int k=0;k<4;k++){ int i=base+k; if (i<N){ rowptr[i]=run; run += v[k]; } }
}

// ---- fused placement for both relations (uses pre-zeroed cnt2 buffers) ----
__global__ __launch_bounds__(256) void place2(const int* __restrict__ src, const int* __restrict__ dst,
    const int* __restrict__ rp_r, const int* __restrict__ rp_rb,
    int* __restrict__ cnt_p, int* __restrict__ cnt_c,
    int* __restrict__ si_r, int* __restrict__ si_rb, int E)
{
  int e = blockIdx.x*256 + threadIdx.x;
  if (e >= E) return;
  int s = src[e], d = dst[e];
  si_r [rp_r [d] + atomicAdd(&cnt_p[d], 1)] = s;
  si_rb[rp_rb[s] + atomicAdd(&cnt_c[s], 1)] = d;
}

// ---- aggregation v2: lanes split (side, colgroup); uint4 row loads; single pass ----
__global__ __launch_bounds__(256) void agg_kernel(
    const int* __restrict__ rowptr, const int* __restrict__ srcidx,
    const float* __restrict__ sSrc, const float* __restrict__ sDst,
    const unsigned short* __restrict__ H, unsigned short* __restrict__ out, int N)
{
  int wv = threadIdx.x >> 6, lane = threadIdx.x & 63;
  int n = blockIdx.x*4 + wv;
  if (n >= N) return;
  int e0 = rowptr[n], e1 = rowptr[n+1];
  int j = lane & 31;
  int side = lane >> 5;
  int h = j >> 2;
  float sdh = sDst[(long long)n*8 + h];
  float a0=0,a1=0,a2=0,a3=0,a4=0,a5=0,a6=0,a7=0, da=0.f;
  float b0=0,b1=0,b2=0,b3=0,b4=0,b5=0,b6=0,b7=0, db=0.f;
  int e = e0 + side;
  for (; e + 2 < e1; e += 4){
    int sA = srcidx[e], sB = srcidx[e+2];
    float lA = sSrc[(long long)sA*8 + h] + sdh;
    float lB = sSrc[(long long)sB*8 + h] + sdh;
    uint4 uA = *(const uint4*)&H[(long long)sA*256 + j*8];
    uint4 uB = *(const uint4*)&H[(long long)sB*256 + j*8];
    float wA = __expf(lA > 0.f ? lA : 0.2f*lA);
    float wB = __expf(lB > 0.f ? lB : 0.2f*lB);
    da += wA; db += wB;
    a0 = fmaf(wA, b2f((unsigned short)(uA.x&0xffffu)), a0);
    a1 = fmaf(wA, b2f((unsigned short)(uA.x>>16)),     a1);
    a2 = fmaf(wA, b2f((unsigned short)(uA.y&0xffffu)), a2);
    a3 = fmaf(wA, b2f((unsigned short)(uA.y>>16)),     a3);
    a4 = fmaf(wA, b2f((unsigned short)(uA.z&0xffffu)), a4);
    a5 = fmaf(wA, b2f((unsigned short)(uA.z>>16)),     a5);
    a6 = fmaf(wA, b2f((unsigned short)(uA.w&0xffffu)), a6);
    a7 = fmaf(wA, b2f((unsigned short)(uA.w>>16)),     a7);
    b0 = fmaf(wB, b2f((unsigned short)(uB.x&0xffffu)), b0);
    b1 = fmaf(wB, b2f((unsigned short)(uB.x>>16)),     b1);
    b2 = fmaf(wB, b2f((unsigned short)(uB.y&0xffffu)), b2);
    b3 = fmaf(wB, b2f((unsigned short)(uB.y>>16)),     b3);
    b4 = fmaf(wB, b2f((unsigned short)(uB.z&0xffffu)), b4);
    b5 = fmaf(wB, b2f((unsigned short)(uB.z>>16)),     b5);
    b6 = fmaf(wB, b2f((unsigned short)(uB.w&0xffffu)), b6);
    b7 = fmaf(wB, b2f((unsigned short)(uB.w>>16)),     b7);
  }
  for (; e < e1; e += 2){
    int s = srcidx[e];
    float l = sSrc[(long long)s*8 + h] + sdh;
    uint4 u = *(const uint4*)&H[(long long)s*256 + j*8];
    float w = __expf(l > 0.f ? l : 0.2f*l);
    da += w;
    a0 = fmaf(w, b2f((unsigned short)(u.x&0xffffu)), a0);
    a1 = fmaf(w, b2f((unsigned short)(u.x>>16)),     a1);
    a2 = fmaf(w, b2f((unsigned short)(u.y&0xffffu)), a2);
    a3 = fmaf(w, b2f((unsigned short)(u.y>>16)),     a3);
    a4 = fmaf(w, b2f((unsigned short)(u.z&0xffffu)), a4);
    a5 = fmaf(w, b2f((unsigned short)(u.z>>16)),     a5);
    a6 = fmaf(w, b2f((unsigned short)(u.w&0xffffu)), a6);
    a7 = fmaf(w, b2f((unsigned short)(u.w>>16)),     a7);
  }
  a0+=b0; a1+=b1; a2+=b2; a3+=b3; a4+=b4; a5+=b5; a6+=b6; a7+=b7;
  da += db;
  a0 += __shfl_xor(a0,32); a1 += __shfl_xor(a1,32);
  a2 += __shfl_xor(a2,32); a3 += __shfl_xor(a3,32);
  a4 += __shfl_xor(a4,32); a5 += __shfl_xor(a5,32);
  a6 += __shfl_xor(a6,32); a7 += __shfl_xor(a7,32);
  da += __shfl_xor(da,32);
  float inv = 1.f/(da + 1e-16f);
  if (side == 0){
    uint4 o;
    o.x = (unsigned)f2b(fmaxf(a0*inv,0.f)) | ((unsigned)f2b(fmaxf(a1*inv,0.f))<<16);
    o.y = (unsigned)f2b(fmaxf(a2*inv,0.f)) | ((unsigned)f2b(fmaxf(a3*inv,0.f))<<16);
    o.z = (unsigned)f2b(fmaxf(a4*inv,0.f)) | ((unsigned)f2b(fmaxf(a5*inv,0.f))<<16);
    o.w = (unsigned)f2b(fmaxf(a6*inv,0.f)) | ((unsigned)f2b(fmaxf(a7*inv,0.f))<<16);
    *(uint4*)&out[(long long)n*256 + j*8] = o;
  }
}

// ---- dense streaming GEMM: Y[M][128] = A[M][256] @ Bt^T (both bf16, fp32 acc) ----
__global__ __launch_bounds__(256) void gemmY(const unsigned short* __restrict__ A,
    const unsigned short* __restrict__ Bt, unsigned short* __restrict__ Y, int M)
{
  __shared__ unsigned short feat[32*264];
  int tid = threadIdx.x;
  int wv = tid>>6, lane = tid&63;
  long long base = (long long)blockIdx.x*32;
  #pragma unroll
  for (int i=0;i<8;i++){
    int r = wv*8 + i;
    if (lane < 32) gl2lds16(A + (base+r)*256 + lane*8, &feat[r*264]);
  }
  __syncthreads();
  int m = lane&31, hi = lane>>5;
  f32x16 acc;
  #pragma unroll
  for (int i=0;i<16;i++) acc[i]=0.f;
  const unsigned short* ap  = feat + m*264 + hi*8;
  const unsigned short* btp = Bt + (wv*32 + m)*256 + hi*8;
  #pragma unroll 4
  for (int ks=0; ks<16; ks++){
    bf16x8 a = *(const bf16x8*)(ap + ks*16);
    bf16x8 b = *(const bf16x8*)(btp + ks*16);
    acc = __builtin_amdgcn_mfma_f32_32x32x16_bf16(a, b, acc, 0, 0, 0);
  }
  int col = wv*32 + m;
  #pragma unroll
  for (int reg=0; reg<16; reg++){
    int row = (reg&3) + 8*(reg>>2) + 4*hi;
    Y[(base+row)*128 + col] = f2b(acc[reg]);
  }
}

// ---- gather + sum + relu + BN1 stats (grid-stride, register stat accumulation) ----
// x1 = relu(Yc[ls]+Yp[ld]+Ts[si]+Tc[ci]+Tg[gi]); stats atomics ONCE per block (R14 fix:
// 12500 blocks x 256 same-line atomics serialized ~300us; now 2048 x 256)
__global__ __launch_bounds__(256) void gather_fc1(
    const unsigned short* __restrict__ Yc, const unsigned short* __restrict__ Yp,
    const float* __restrict__ Ts, const float* __restrict__ Tc, const float* __restrict__ Tg,
    const int* __restrict__ lsrc, const int* __restrict__ ldst,
    const int* __restrict__ sidx, const int* __restrict__ cidx, const int* __restrict__ gidx,
    unsigned short* __restrict__ x1, float* __restrict__ bnsum, int ntiles)
{
  __shared__ float redS[16][128];
  __shared__ float redQ[16][128];
  int tid = threadIdx.x;
  int rl = tid>>4, g = tid&15;             // 16 rows x 16 col-groups of 8
  float sacc[8] = {0,0,0,0,0,0,0,0};
  float qacc[8] = {0,0,0,0,0,0,0,0};
  for (int t = blockIdx.x; t < ntiles; t += gridDim.x){
    long long row = (long long)t*16 + rl;
    int ls = lsrc[row], ld = ldst[row], si = sidx[row], ci = cidx[row], gi = gidx[row];
    uint4 uc = *(const uint4*)&Yc[(long long)ls*128 + g*8];
    uint4 up = *(const uint4*)&Yp[(long long)ld*128 + g*8];
    float4 t0 = *(const float4*)&Ts[si*128 + g*8];
    float4 t1 = *(const float4*)&Ts[si*128 + g*8 + 4];
    float4 c0 = *(const float4*)&Tc[ci*128 + g*8];
    float4 c1 = *(const float4*)&Tc[ci*128 + g*8 + 4];
    float4 g0 = *(const float4*)&Tg[gi*128 + g*8];
    float4 g1 = *(const float4*)&Tg[gi*128 + g*8 + 4];
    unsigned ucs[4] = {uc.x,uc.y,uc.z,uc.w};
    unsigned ups[4] = {up.x,up.y,up.z,up.w};
    float tb[8] = {t0.x+c0.x+g0.x, t0.y+c0.y+g0.y, t0.z+c0.z+g0.z, t0.w+c0.w+g0.w,
                   t1.x+c1.x+g1.x, t1.y+c1.y+g1.y, t1.z+c1.z+g1.z, t1.w+c1.w+g1.w};
    unsigned short ov[8];
    #pragma unroll
    for (int p=0;p<4;p++){
      float vl = b2f((unsigned short)(ucs[p]&0xffffu)) + b2f((unsigned short)(ups[p]&0xffffu)) + tb[p*2];
      float vh = b2f((unsigned short)(ucs[p]>>16))     + b2f((unsigned short)(ups[p]>>16))     + tb[p*2+1];
      vl = fmaxf(vl, 0.f); vh = fmaxf(vh, 0.f);
      ov[p*2] = f2b(vl); ov[p*2+1] = f2b(vh);
      sacc[p*2]   += vl; qacc[p*2]   += vl*vl;
      sacc[p*2+1] += vh; qacc[p*2+1] += vh*vh;
    }
    *(uint4*)&x1[row*128 + g*8] = *(uint4*)ov;
  }
  #pragma unroll
  for (int j=0;j<8;j++){ redS[rl][g*8+j]=sacc[j]; redQ[rl][g*8+j]=qacc[j]; }
  __syncthreads();
  if (tid < 128){
    float s=0.f, q=0.f;
    #pragma unroll
    for (int r=0;r<16;r++){ s += redS[r][tid]; q += redQ[r][tid]; }
    atomicAdd(&bnsum[tid], s);
    atomicAdd(&bnsum[128+tid], q);
  }
}

// ---- T2: fold BN1 into fc2 ----
__global__ void bn1_fold(const float* __restrict__ bnsum,
    const float* __restrict__ gamma, const float* __restrict__ beta,
    const float* __restrict__ fc2W, const float* __restrict__ fc2b,
    float* __restrict__ fc2p, float* __restrict__ b2p, float invB)
{
  __shared__ float sc[128], sh[128];
  int tid = threadIdx.x;
  if (tid<128){
    float mu  = bnsum[tid]*invB;
    float var = bnsum[128+tid]*invB - mu*mu;
    float s = gamma[tid] * rsqrtf(var + 1e-5f);
    sc[tid]=s; sh[tid]= beta[tid] - mu*s;
  }
  __syncthreads();
  for (int idx=tid; idx<128*32; idx+=256){ int k=idx>>5; fc2p[idx] = sc[k]*fc2W[idx]; }
  if (tid<32){
    float a = fc2b[tid];
    for (int k=0;k<128;k++) a = fmaf(sh[k], fc2W[k*32+tid], a);
    b2p[tid]=a;
  }
}

// ---- T3: x2 = relu(x1 @ fc2' + b2') bf16, BN2 stats ----
__global__ __launch_bounds__(256) void fc2_kernel(const unsigned short* __restrict__ x1,
    const float* __restrict__ fc2p, const float* __restrict__ b2p,
    unsigned short* __restrict__ x2, float* __restrict__ bnsum2)
{
  __shared__ float xt[64*128];
  __shared__ float Wl[128*32];
  __shared__ float redS[8][32];
  __shared__ float redQ[8][32];
  int tid = threadIdx.x;
  for (int idx=tid; idx<4096; idx+=256) Wl[idx]=fc2p[idx];
  long long base = (long long)blockIdx.x*64;
  const unsigned* x1u = (const unsigned*)x1;
  for (int idx=tid; idx<64*64; idx+=256){
    unsigned u = x1u[base*64 + idx];
    xt[idx*2]   = b2f((unsigned short)(u&0xffffu));
    xt[idx*2+1] = b2f((unsigned short)(u>>16));
  }
  __syncthreads();
  int tx=tid&31, ty=tid>>5;
  float acc[8];
  float bb=b2p[tx];
  #pragma unroll
  for (int i=0;i<8;i++) acc[i]=bb;
  for (int k=0;k<128;k++){
    float w=Wl[k*32+tx];
    #pragma unroll
    for (int i=0;i<8;i++) acc[i]=fmaf(xt[(ty*8+i)*128+k], w, acc[i]);
  }
  float s=0,q=0;
  #pragma unroll
  for (int i=0;i<8;i++){
    float v=fmaxf(acc[i],0.f);
    x2[(base+ty*8+i)*32+tx]=f2b(v);
    s+=v; q+=v*v;
  }
  redS[ty][tx]=s; redQ[ty][tx]=q;
  __syncthreads();
  if (tid<32){
    float a=0,b=0;
    #pragma unroll
    for (int j=0;j<8;j++){ a+=redS[j][tid]; b+=redQ[j][tid]; }
    atomicAdd(&bnsum2[tid],a); atomicAdd(&bnsum2[32+tid],b);
  }
}

// ---- T4: fold BN2 into fc3 ----
__global__ void bn2_fold(const float* __restrict__ bnsum2,
    const float* __restrict__ gamma2, const float* __restrict__ beta2,
    const float* __restrict__ fc3W, const float* __restrict__ fc3b,
    float* __restrict__ w3p, float invB)
{
  __shared__ float sh3[32];
  int tid = threadIdx.x;
  if (tid<32){
    float mu  = bnsum2[tid]*invB;
    float var = bnsum2[32+tid]*invB - mu*mu;
    float s   = gamma2[tid] * rsqrtf(var + 1e-5f);
    float shv = beta2[tid] - mu*s;
    float w   = fc3W[tid];
    w3p[tid]  = s*w;
    sh3[tid]  = shv*w;
  }
  __syncthreads();
  if (tid==0){
    float a = fc3b[0];
    for (int j=0;j<32;j++) a += sh3[j];
    w3p[32] = a;
  }
}

// ---- T5: out = x2 @ w3' + b3' (fp32 out) ----
__global__ __launch_bounds__(256) void fc3_kernel(const unsigned short* __restrict__ x2,
    const float* __restrict__ w3p, float* __restrict__ out)
{
  __shared__ float wl[34];
  int tid = threadIdx.x;
  if (tid<33) wl[tid]=w3p[tid];
  __syncthreads();
  long long row = (long long)blockIdx.x*32 + (tid>>3);
  int j0 = (tid&7)*4;
  uint2 u = *(const uint2*)(x2 + row*32 + j0);
  float a = b2f((unsigned short)(u.x&0xffffu))*wl[j0]
          + b2f((unsigned short)(u.x>>16))   *wl[j0+1]
          + b2f((unsigned short)(u.y&0xffffu))*wl[j0+2]
          + b2f((unsigned short)(u.y>>16))   *wl[j0+3];
  a += __shfl_xor(a,1);
  a += __shfl_xor(a,2);
  a += __shfl_xor(a,4);
  if ((tid&7)==0) out[row] = a + wl[32];
}

extern "C" void kernel_launch(void* const* d_in, const int* in_sizes, int n_in,
                              void* d_out, int out_size, void* d_ws, size_t ws_size,
                              hipStream_t stream)
{
  (void)in_sizes; (void)n_in; (void)out_size; (void)ws_size;
  const float* customer_x = (const float*)d_in[0];
  const float* product_x  = (const float*)d_in[1];
  const float* pcW = (const float*)d_in[2];
  const float* pcB = (const float*)d_in[3];
  const float* ppW = (const float*)d_in[4];
  const float* ppB = (const float*)d_in[5];
  const float* att_src_r  = (const float*)d_in[6];
  const float* att_dst_r  = (const float*)d_in[7];
  const float* att_src_rb = (const float*)d_in[8];
  const float* att_dst_rb = (const float*)d_in[9];
  // d_in[10..12] dead (semantic softmax over 1 metapath == 1)
  const float* color_emb = (const float*)d_in[13];
  const float* size_emb  = (const float*)d_in[14];
  const float* group_emb = (const float*)d_in[15];
  const float* fc1W = (const float*)d_in[16];
  const float* fc1b = (const float*)d_in[17];
  const float* fc2W = (const float*)d_in[18];
  const float* fc2b = (const float*)d_in[19];
  const float* fc3W = (const float*)d_in[20];
  const float* fc3b = (const float*)d_in[21];
  const float* bn1g = (const float*)d_in[22];
  const float* bn1b = (const float*)d_in[23];
  const float* bn2g = (const float*)d_in[24];
  const float* bn2b = (const float*)d_in[25];
  const int* edge_src  = (const int*)d_in[26];
  const int* edge_dst  = (const int*)d_in[27];
  const int* label_src = (const int*)d_in[28];
  const int* label_dst = (const int*)d_in[29];
  const int* size_idx  = (const int*)d_in[30];
  const int* color_idx = (const int*)d_in[31];
  const int* group_idx = (const int*)d_in[32];

  char* ws = (char*)d_ws;
  size_t off = 0;
  auto alloc = [&](size_t bytes)->char* {
    char* p = ws + off;
    off += (bytes + 255) & ~(size_t)255;
    return p;
  };
  // ~236 MB peak (< 256 MiB hard limit)
  unsigned short* H_c  = (unsigned short*)alloc((size_t)NCC*256*2);   // H_c -> out_c -> x1
  unsigned short* H_p  = (unsigned short*)alloc((size_t)NPRR*256*2);  // H_p -> Y_p
  unsigned short* out_p= (unsigned short*)alloc((size_t)NPRR*256*2);  // out_p -> Y_c
  float* s_cr     = (float*)alloc((size_t)NCC*8*4);     // x2b aliases after aggs
  float* s_crb    = (float*)alloc((size_t)NCC*8*4);
  float* s_pr     = (float*)alloc((size_t)NPRR*8*4);
  float* s_prb    = (float*)alloc((size_t)NPRR*8*4);
  int* rowptr_r   = (int*)alloc((size_t)(NPRR+1)*4);
  int* rowptr_rb  = (int*)alloc((size_t)(NCC+1)*4);
  int* srcidx_r   = (int*)alloc((size_t)NEE*4);
  int* srcidx_rb  = (int*)alloc((size_t)NEE*4);
  int* cnts       = (int*)alloc((size_t)(NCC+NPRR)*2*4);
  int* cnt_c      = cnts;
  int* cnt_p      = cnts + NCC;
  int* cnt_c2     = cnts + NCC + NPRR;
  int* cnt_p2     = cnts + NCC + NPRR + NCC;
  int* bsum_c     = (int*)alloc(256*4);
  int* bsum_p     = (int*)alloc(256*4);
  unsigned short* BtC = (unsigned short*)alloc(128*256*2);
  unsigned short* BtP = (unsigned short*)alloc(128*256*2);
  float* Ts     = (float*)alloc(30*128*4);
  float* Tc     = (float*)alloc(1000*128*4);
  float* Tg     = (float*)alloc(50*128*4);
  float* wa_c   = (float*)alloc(272*4);
  float* wa_p   = (float*)alloc(272*4);
  float* bnsum1 = (float*)alloc(256*4);
  float* bnsum2 = (float*)alloc(64*4);
  float* fc2p   = (float*)alloc(4096*4);
  float* b2p    = (float*)alloc(32*4);
  float* w3p    = (float*)alloc(34*4);
  unsigned short* out_c = H_c;                   // H_c dead after agg_r
  unsigned short* Y_p   = H_p;                   // H_p dead after agg_rb
  unsigned short* Y_c   = out_p;                 // out_p dead after gemmY_p
  unsigned short* x1b   = H_c;                   // out_c dead after gemmY_c
  unsigned short* x2b   = (unsigned short*)s_cr; // scores dead after aggs

  hipMemsetAsync(bnsum1, 0, 1280, stream);       // bnsum1+bnsum2 contiguous
  hipMemsetAsync(cnts, 0, (size_t)(NCC+NPRR)*2*4, stream);

  // prep: WA (scores), fc1 restructure tables/weights
  wa_prep2<<<1,256,0,stream>>>(pcW, pcB, att_src_r, att_dst_rb,
                               ppW, ppB, att_dst_r, att_src_rb, wa_c, wa_p);
  prep_fc1<<<(203776+255)/256,256,0,stream>>>(fc1W, fc1b, size_emb, color_emb, group_emb,
      BtC, BtP, Ts, Tc, Tg);

  // proj + fused scores
  proj_kernel<<<2048,256,0,stream>>>(customer_x, pcW, pcB, wa_c, H_c, s_cr, s_crb, NCC);
  proj_kernel<<<2048,256,0,stream>>>(product_x,  ppW, ppB, wa_p, H_p, s_pr, s_prb, NPRR);

  // CSR build (both relations)
  const int eg = (NEE+255)/256;
  const int BP = (NPRR+1023)/1024;   // 98
  const int BC = (NCC +1023)/1024;   // 196
  hist2<<<eg,256,0,stream>>>(edge_src, edge_dst, cnt_c, cnt_p, NEE);
  scan_phase1<<<BP,256,0,stream>>>(cnt_p, bsum_p, NPRR);
  scan_phase2<<<1,256,0,stream>>>(bsum_p, BP, rowptr_r, NPRR);
  scan_phase3<<<BP,256,0,stream>>>(cnt_p, bsum_p, rowptr_r, NPRR);
  scan_phase1<<<BC,256,0,stream>>>(cnt_c, bsum_c, NCC);
  scan_phase2<<<1,256,0,stream>>>(bsum_c, BC, rowptr_rb, NCC);
  scan_phase3<<<BC,256,0,stream>>>(cnt_c, bsum_c, rowptr_rb, NCC);
  place2<<<eg,256,0,stream>>>(edge_src, edge_dst, rowptr_r, rowptr_rb,
      cnt_p2, cnt_c2, srcidx_r, srcidx_rb, NEE);

  // single-pass gather aggregation
  agg_kernel<<<(NPRR+3)/4,256,0,stream>>>(rowptr_r,  srcidx_r,  s_cr,  s_pr,  H_c, out_p, NPRR);
  agg_kernel<<<(NCC +3)/4,256,0,stream>>>(rowptr_rb, srcidx_rb, s_prb, s_crb, H_p, out_c, NCC);

  // restructured fc1: dense GEMMs (streaming) + grid-stride gather-add
  gemmY<<<NPRR/32,256,0,stream>>>(out_p, BtP, Y_p, NPRR);   // out_p consumed -> Y_c may overwrite
  gemmY<<<NCC/32,256,0,stream>>>(out_c, BtC, Y_c, NCC);     // out_c consumed -> x1 may overwrite
  gather_fc1<<<2048,256,0,stream>>>(Y_c, Y_p, Ts, Tc, Tg,
      label_src, label_dst, size_idx, color_idx, group_idx, x1b, bnsum1, NBB/16);

  bn1_fold<<<1,256,0,stream>>>(bnsum1, bn1g, bn1b, fc2W, fc2b, fc2p, b2p, 1.0f/NBB);
  fc2_kernel<<<NBB/64,256,0,stream>>>(x1b, fc2p, b2p, x2b, bnsum2);
  bn2_fold<<<1,64,0,stream>>>(bnsum2, bn2g, bn2b, fc3W, fc3b, w3p, 1.0f/NBB);
  fc3_kernel<<<NBB/32,256,0,stream>>>(x2b, w3p, (float*)d_out);
}

// Round 16
// 693.740 us; speedup vs baseline: 1.4006x; 1.0626x over previous
//
#include <hip/hip_runtime.h>

#define NCC 200000
#define NPRR 100000
#define NEE 500000
#define NBB 200000

typedef __attribute__((ext_vector_type(8))) short bf16x8;
typedef __attribute__((ext_vector_type(16))) float f32x16;

__device__ __forceinline__ float b2f(unsigned short u){ return __uint_as_float(((unsigned)u)<<16); }
__device__ __forceinline__ unsigned short f2b(float f){
  unsigned x = __float_as_uint(f);
  return (unsigned short)((x + 0x7fffu + ((x>>16)&1u)) >> 16);
}
// async global->LDS DMA, 16B/lane; LDS dest = uniform base + lane*16 (HW)
__device__ __forceinline__ void gl2lds16(const void* g, void* l){
  __builtin_amdgcn_global_load_lds(
      (const __attribute__((address_space(1))) unsigned int*)g,
      (__attribute__((address_space(3))) unsigned int*)l, 16, 0, 0);
}

// ---- WA prep (both node types in one launch): WA[set][k][h] ----
__global__ __launch_bounds__(256) void wa_prep2(
    const float* __restrict__ Wc, const float* __restrict__ bc,
    const float* __restrict__ attAc, const float* __restrict__ attBc,
    const float* __restrict__ Wp, const float* __restrict__ bp,
    const float* __restrict__ attAp, const float* __restrict__ attBp,
    float* __restrict__ WAc, float* __restrict__ WAp)
{
  int tid = threadIdx.x;
  for (int task = tid; task < 4*17*8; task += 256) {
    int grp = task / 136, rem = task % 136;
    int k = rem >> 3, h = rem & 7;
    const float* att = (grp==0)?attAc:(grp==1)?attBc:(grp==2)?attAp:attBp;
    const float* W   = (grp<2)?Wc:Wp;
    const float* bias= (grp<2)?bc:bp;
    const float* row = (k < 16) ? (W + k*256) : bias;
    float acc = 0.f;
    for (int d = 0; d < 32; d++) acc = fmaf(row[h*32+d], att[h*32+d], acc);
    if (grp<2) WAc[(grp&1)*136 + rem] = acc;
    else       WAp[(grp&1)*136 + rem] = acc;
  }
}

// ---- prep for restructured fc1: Bt_c/Bt_p (W1 halves, transposed bf16) + emb tables ----
__global__ __launch_bounds__(256) void prep_fc1(const float* __restrict__ fc1W,
    const float* __restrict__ fc1b,
    const float* __restrict__ size_emb, const float* __restrict__ color_emb,
    const float* __restrict__ group_emb,
    unsigned short* __restrict__ BtC, unsigned short* __restrict__ BtP,
    float* __restrict__ Ts, float* __restrict__ Tc, float* __restrict__ Tg)
{
  int idx = blockIdx.x*256 + threadIdx.x;
  if (idx < 32768){                       // BtC[n][k] = W1[k][n], k<256
    int n = idx>>8, k = idx&255;
    BtC[idx] = f2b(fc1W[k*128 + n]);
  } else if (idx < 65536){                // BtP[n][k] = W1[256+k][n]
    int t = idx - 32768;
    int n = t>>8, k = t&255;
    BtP[t] = f2b(fc1W[(256+k)*128 + n]);
  } else if (idx < 65536 + 30*128){       // Ts (bias folded)
    int t = idx - 65536;
    int s = t>>7, j = t&127;
    float a = fc1b[j];
    #pragma unroll
    for (int c=0;c<4;c++) a = fmaf(size_emb[s*4+c], fc1W[(512+c)*128+j], a);
    Ts[t] = a;
  } else if (idx < 65536 + 30*128 + 1000*128){  // Tc
    int t = idx - 65536 - 30*128;
    int col = t>>7, j = t&127;
    float a = 0.f;
    #pragma unroll
    for (int c=0;c<8;c++) a = fmaf(color_emb[col*8+c], fc1W[(516+c)*128+j], a);
    Tc[t] = a;
  } else if (idx < 65536 + 30*128 + 1000*128 + 50*128){  // Tg
    int t = idx - 65536 - 30*128 - 1000*128;
    int g = t>>7, j = t&127;
    float a = 0.f;
    #pragma unroll
    for (int c=0;c<4;c++) a = fmaf(group_emb[g*4+c], fc1W[(524+c)*128+j], a);
    Tg[t] = a;
  }
}

// ---- projection + fused scores: H=X@W+b (bf16), sA/sB = x·(W@att)+b·att ----
__global__ __launch_bounds__(256) void proj_kernel(const float* __restrict__ X,
    const float* __restrict__ W, const float* __restrict__ b,
    const float* __restrict__ WA,
    unsigned short* __restrict__ H, float* __restrict__ sA, float* __restrict__ sB, int N)
{
  __shared__ float Wl[16*256];
  __shared__ float bl[256];
  __shared__ float xs[8*16];
  __shared__ float wa[272];
  int tid = threadIdx.x;
  #pragma unroll
  for (int i=0;i<16;i++) Wl[i*256+tid] = W[i*256+tid];
  bl[tid] = b[tid];
  for (int i=tid;i<272;i+=256) wa[i]=WA[i];
  int nh = tid>>7;
  int c2 = (tid&127)*2;
  for (int base = blockIdx.x*8; base < N; base += gridDim.x*8) {
    __syncthreads();
    if (tid < 128) {
      int n = tid>>4, k = tid&15;
      int node = base + n;
      xs[tid] = (node < N) ? X[(long long)node*16+k] : 0.f;
    }
    __syncthreads();
    if (tid < 128){
      int nn = tid>>4, t = tid&15;
      int set = t>>3, h = t&7;
      int node = base + nn;
      if (node < N){
        const float* w = wa + set*136;
        float a = w[128 + h];
        #pragma unroll
        for (int k=0;k<16;k++) a = fmaf(xs[nn*16+k], w[k*8+h], a);
        (set ? sB : sA)[(long long)node*8 + h] = a;
      }
    }
    #pragma unroll
    for (int np=0;np<4;np++){
      int n = np*2 + nh;
      int node = base+n;
      if (node < N){
        float a0 = bl[c2], a1 = bl[c2+1];
        #pragma unroll
        for (int k=0;k<16;k++){
          float xv = xs[n*16+k];
          a0 = fmaf(xv, Wl[k*256+c2],   a0);
          a1 = fmaf(xv, Wl[k*256+c2+1], a1);
        }
        *(unsigned*)&H[(long long)node*256 + c2] = (unsigned)f2b(a0) | ((unsigned)f2b(a1)<<16);
      }
    }
  }
}

// ---- fused degree histogram for both relations ----
__global__ __launch_bounds__(256) void hist2(const int* __restrict__ src, const int* __restrict__ dst,
    int* __restrict__ cnt_c, int* __restrict__ cnt_p, int E)
{
  int e = blockIdx.x*256 + threadIdx.x;
  if (e >= E) return;
  atomicAdd(&cnt_p[dst[e]], 1);
  atomicAdd(&cnt_c[src[e]], 1);
}

// ---- hierarchical exclusive scan ----
__global__ __launch_bounds__(256) void scan_phase1(const int* __restrict__ cnt, int* __restrict__ bsum, int N)
{
  __shared__ int red[256];
  int tid = threadIdx.x;
  int base = blockIdx.x*1024 + tid*4;
  int s = 0;
  #pragma unroll
  for (int k=0;k<4;k++){ int i=base+k; if (i<N) s += cnt[i]; }
  red[tid] = s;
  __syncthreads();
  for (int off=128; off>0; off>>=1){ if (tid<off) red[tid]+=red[tid+off]; __syncthreads(); }
  if (tid==0) bsum[blockIdx.x] = red[0];
}

__global__ __launch_bounds__(256) void scan_phase2(int* __restrict__ bsum, int B,
    int* __restrict__ rowptr, int N)
{
  __shared__ int ts[256];
  int tid = threadIdx.x;
  int v = (tid<B) ? bsum[tid] : 0;
  ts[tid] = v;
  __syncthreads();
  for (int off=1; off<256; off<<=1){
    int t = (tid>=off) ? ts[tid-off] : 0;
    __syncthreads();
    ts[tid] += t;
    __syncthreads();
  }
  if (tid < B) bsum[tid] = ts[tid] - v;
  if (tid == B-1) rowptr[N] = ts[tid];
}

__global__ __launch_bounds__(256) void scan_phase3(const int* __restrict__ cnt,
    const int* __restrict__ bsum, int* __restrict__ rowptr, int N)
{
  __shared__ int ts[256];
  int tid = threadIdx.x;
  int base = blockIdx.x*1024 + tid*4;
  int v[4]; int s = 0;
  #pragma unroll
  for (int k=0;k<4;k++){ int i=base+k; v[k] = (i<N) ? cnt[i] : 0; s += v[k]; }
  ts[tid] = s;
  __syncthreads();
  for (int off=1; off<256; off<<=1){
    int t = (tid>=off) ? ts[tid-off] : 0;
    __syncthreads();
    ts[tid] += t;
    __syncthreads();
  }
  int run = bsum[blockIdx.x] + ts[tid] - s;
  #pragma unroll
  for (int k=0;k<4;k++){ int i=base+k; if (i<N){ rowptr[i]=run; run += v[k]; } }
}

// ---- fused placement for both relations (uses pre-zeroed cnt2 buffers) ----
__global__ __launch_bounds__(256) void place2(const int* __restrict__ src, const int* __restrict__ dst,
    const int* __restrict__ rp_r, const int* __restrict__ rp_rb,
    int* __restrict__ cnt_p, int* __restrict__ cnt_c,
    int* __restrict__ si_r, int* __restrict__ si_rb, int E)
{
  int e = blockIdx.x*256 + threadIdx.x;
  if (e >= E) return;
  int s = src[e], d = dst[e];
  si_r [rp_r [d] + atomicAdd(&cnt_p[d], 1)] = s;
  si_rb[rp_rb[s] + atomicAdd(&cnt_c[s], 1)] = d;
}

// ---- aggregation v2: lanes split (side, colgroup); uint4 row loads; single pass ----
__global__ __launch_bounds__(256) void agg_kernel(
    const int* __restrict__ rowptr, const int* __restrict__ srcidx,
    const float* __restrict__ sSrc, const float* __restrict__ sDst,
    const unsigned short* __restrict__ H, unsigned short* __restrict__ out, int N)
{
  int wv = threadIdx.x >> 6, lane = threadIdx.x & 63;
  int n = blockIdx.x*4 + wv;
  if (n >= N) return;
  int e0 = rowptr[n], e1 = rowptr[n+1];
  int j = lane & 31;
  int side = lane >> 5;
  int h = j >> 2;
  float sdh = sDst[(long long)n*8 + h];
  float a0=0,a1=0,a2=0,a3=0,a4=0,a5=0,a6=0,a7=0, da=0.f;
  float b0=0,b1=0,b2=0,b3=0,b4=0,b5=0,b6=0,b7=0, db=0.f;
  int e = e0 + side;
  for (; e + 2 < e1; e += 4){
    int sA = srcidx[e], sB = srcidx[e+2];
    float lA = sSrc[(long long)sA*8 + h] + sdh;
    float lB = sSrc[(long long)sB*8 + h] + sdh;
    uint4 uA = *(const uint4*)&H[(long long)sA*256 + j*8];
    uint4 uB = *(const uint4*)&H[(long long)sB*256 + j*8];
    float wA = __expf(lA > 0.f ? lA : 0.2f*lA);
    float wB = __expf(lB > 0.f ? lB : 0.2f*lB);
    da += wA; db += wB;
    a0 = fmaf(wA, b2f((unsigned short)(uA.x&0xffffu)), a0);
    a1 = fmaf(wA, b2f((unsigned short)(uA.x>>16)),     a1);
    a2 = fmaf(wA, b2f((unsigned short)(uA.y&0xffffu)), a2);
    a3 = fmaf(wA, b2f((unsigned short)(uA.y>>16)),     a3);
    a4 = fmaf(wA, b2f((unsigned short)(uA.z&0xffffu)), a4);
    a5 = fmaf(wA, b2f((unsigned short)(uA.z>>16)),     a5);
    a6 = fmaf(wA, b2f((unsigned short)(uA.w&0xffffu)), a6);
    a7 = fmaf(wA, b2f((unsigned short)(uA.w>>16)),     a7);
    b0 = fmaf(wB, b2f((unsigned short)(uB.x&0xffffu)), b0);
    b1 = fmaf(wB, b2f((unsigned short)(uB.x>>16)),     b1);
    b2 = fmaf(wB, b2f((unsigned short)(uB.y&0xffffu)), b2);
    b3 = fmaf(wB, b2f((unsigned short)(uB.y>>16)),     b3);
    b4 = fmaf(wB, b2f((unsigned short)(uB.z&0xffffu)), b4);
    b5 = fmaf(wB, b2f((unsigned short)(uB.z>>16)),     b5);
    b6 = fmaf(wB, b2f((unsigned short)(uB.w&0xffffu)), b6);
    b7 = fmaf(wB, b2f((unsigned short)(uB.w>>16)),     b7);
  }
  for (; e < e1; e += 2){
    int s = srcidx[e];
    float l = sSrc[(long long)s*8 + h] + sdh;
    uint4 u = *(const uint4*)&H[(long long)s*256 + j*8];
    float w = __expf(l > 0.f ? l : 0.2f*l);
    da += w;
    a0 = fmaf(w, b2f((unsigned short)(u.x&0xffffu)), a0);
    a1 = fmaf(w, b2f((unsigned short)(u.x>>16)),     a1);
    a2 = fmaf(w, b2f((unsigned short)(u.y&0xffffu)), a2);
    a3 = fmaf(w, b2f((unsigned short)(u.y>>16)),     a3);
    a4 = fmaf(w, b2f((unsigned short)(u.z&0xffffu)), a4);
    a5 = fmaf(w, b2f((unsigned short)(u.z>>16)),     a5);
    a6 = fmaf(w, b2f((unsigned short)(u.w&0xffffu)), a6);
    a7 = fmaf(w, b2f((unsigned short)(u.w>>16)),     a7);
  }
  a0+=b0; a1+=b1; a2+=b2; a3+=b3; a4+=b4; a5+=b5; a6+=b6; a7+=b7;
  da += db;
  a0 += __shfl_xor(a0,32); a1 += __shfl_xor(a1,32);
  a2 += __shfl_xor(a2,32); a3 += __shfl_xor(a3,32);
  a4 += __shfl_xor(a4,32); a5 += __shfl_xor(a5,32);
  a6 += __shfl_xor(a6,32); a7 += __shfl_xor(a7,32);
  da += __shfl_xor(da,32);
  float inv = 1.f/(da + 1e-16f);
  if (side == 0){
    uint4 o;
    o.x = (unsigned)f2b(fmaxf(a0*inv,0.f)) | ((unsigned)f2b(fmaxf(a1*inv,0.f))<<16);
    o.y = (unsigned)f2b(fmaxf(a2*inv,0.f)) | ((unsigned)f2b(fmaxf(a3*inv,0.f))<<16);
    o.z = (unsigned)f2b(fmaxf(a4*inv,0.f)) | ((unsigned)f2b(fmaxf(a5*inv,0.f))<<16);
    o.w = (unsigned)f2b(fmaxf(a6*inv,0.f)) | ((unsigned)f2b(fmaxf(a7*inv,0.f))<<16);
    *(uint4*)&out[(long long)n*256 + j*8] = o;
  }
}

// ---- dense streaming GEMM: Y[M][128] = A[M][256] @ Bt^T (both bf16, fp32 acc) ----
__global__ __launch_bounds__(256) void gemmY(const unsigned short* __restrict__ A,
    const unsigned short* __restrict__ Bt, unsigned short* __restrict__ Y, int M)
{
  __shared__ unsigned short feat[32*264];
  int tid = threadIdx.x;
  int wv = tid>>6, lane = tid&63;
  long long base = (long long)blockIdx.x*32;
  #pragma unroll
  for (int i=0;i<8;i++){
    int r = wv*8 + i;
    if (lane < 32) gl2lds16(A + (base+r)*256 + lane*8, &feat[r*264]);
  }
  __syncthreads();
  int m = lane&31, hi = lane>>5;
  f32x16 acc;
  #pragma unroll
  for (int i=0;i<16;i++) acc[i]=0.f;
  const unsigned short* ap  = feat + m*264 + hi*8;
  const unsigned short* btp = Bt + (wv*32 + m)*256 + hi*8;
  #pragma unroll 4
  for (int ks=0; ks<16; ks++){
    bf16x8 a = *(const bf16x8*)(ap + ks*16);
    bf16x8 b = *(const bf16x8*)(btp + ks*16);
    acc = __builtin_amdgcn_mfma_f32_32x32x16_bf16(a, b, acc, 0, 0, 0);
  }
  int col = wv*32 + m;
  #pragma unroll
  for (int reg=0; reg<16; reg++){
    int row = (reg&3) + 8*(reg>>2) + 4*hi;
    Y[(base+row)*128 + col] = f2b(acc[reg]);
  }
}

// ---- gather + sum + relu + BN1 stats (grid-stride, register stat accumulation) ----
__global__ __launch_bounds__(256) void gather_fc1(
    const unsigned short* __restrict__ Yc, const unsigned short* __restrict__ Yp,
    const float* __restrict__ Ts, const float* __restrict__ Tc, const float* __restrict__ Tg,
    const int* __restrict__ lsrc, const int* __restrict__ ldst,
    const int* __restrict__ sidx, const int* __restrict__ cidx, const int* __restrict__ gidx,
    unsigned short* __restrict__ x1, float* __restrict__ bnsum, int ntiles)
{
  __shared__ float redS[16][128];
  __shared__ float redQ[16][128];
  int tid = threadIdx.x;
  int rl = tid>>4, g = tid&15;             // 16 rows x 16 col-groups of 8
  float sacc[8] = {0,0,0,0,0,0,0,0};
  float qacc[8] = {0,0,0,0,0,0,0,0};
  for (int t = blockIdx.x; t < ntiles; t += gridDim.x){
    long long row = (long long)t*16 + rl;
    int ls = lsrc[row], ld = ldst[row], si = sidx[row], ci = cidx[row], gi = gidx[row];
    uint4 uc = *(const uint4*)&Yc[(long long)ls*128 + g*8];
    uint4 up = *(const uint4*)&Yp[(long long)ld*128 + g*8];
    float4 t0 = *(const float4*)&Ts[si*128 + g*8];
    float4 t1 = *(const float4*)&Ts[si*128 + g*8 + 4];
    float4 c0 = *(const float4*)&Tc[ci*128 + g*8];
    float4 c1 = *(const float4*)&Tc[ci*128 + g*8 + 4];
    float4 g0 = *(const float4*)&Tg[gi*128 + g*8];
    float4 g1 = *(const float4*)&Tg[gi*128 + g*8 + 4];
    unsigned ucs[4] = {uc.x,uc.y,uc.z,uc.w};
    unsigned ups[4] = {up.x,up.y,up.z,up.w};
    float tb[8] = {t0.x+c0.x+g0.x, t0.y+c0.y+g0.y, t0.z+c0.z+g0.z, t0.w+c0.w+g0.w,
                   t1.x+c1.x+g1.x, t1.y+c1.y+g1.y, t1.z+c1.z+g1.z, t1.w+c1.w+g1.w};
    unsigned short ov[8];
    #pragma unroll
    for (int p=0;p<4;p++){
      float vl = b2f((unsigned short)(ucs[p]&0xffffu)) + b2f((unsigned short)(ups[p]&0xffffu)) + tb[p*2];
      float vh = b2f((unsigned short)(ucs[p]>>16))     + b2f((unsigned short)(ups[p]>>16))     + tb[p*2+1];
      vl = fmaxf(vl, 0.f); vh = fmaxf(vh, 0.f);
      ov[p*2] = f2b(vl); ov[p*2+1] = f2b(vh);
      sacc[p*2]   += vl; qacc[p*2]   += vl*vl;
      sacc[p*2+1] += vh; qacc[p*2+1] += vh*vh;
    }
    *(uint4*)&x1[row*128 + g*8] = *(uint4*)ov;
  }
  #pragma unroll
  for (int j=0;j<8;j++){ redS[rl][g*8+j]=sacc[j]; redQ[rl][g*8+j]=qacc[j]; }
  __syncthreads();
  if (tid < 128){
    float s=0.f, q=0.f;
    #pragma unroll
    for (int r=0;r<16;r++){ s += redS[r][tid]; q += redQ[r][tid]; }
    atomicAdd(&bnsum[tid], s);
    atomicAdd(&bnsum[128+tid], q);
  }
}

// ---- T2: fold BN1 into fc2, emit bf16 transposed weights Bt2[32][128] + fp32 bias ----
__global__ void bn1_fold(const float* __restrict__ bnsum,
    const float* __restrict__ gamma, const float* __restrict__ beta,
    const float* __restrict__ fc2W, const float* __restrict__ fc2b,
    unsigned short* __restrict__ Bt2, float* __restrict__ b2p, float invB)
{
  __shared__ float sc[128], sh[128];
  int tid = threadIdx.x;
  if (tid<128){
    float mu  = bnsum[tid]*invB;
    float var = bnsum[128+tid]*invB - mu*mu;
    float s = gamma[tid] * rsqrtf(var + 1e-5f);
    sc[tid]=s; sh[tid]= beta[tid] - mu*s;
  }
  __syncthreads();
  for (int idx=tid; idx<32*128; idx+=256){
    int n = idx>>7, k = idx&127;
    Bt2[idx] = f2b(sc[k]*fc2W[k*32+n]);
  }
  if (tid<32){
    float a = fc2b[tid];
    for (int k=0;k<128;k++) a = fmaf(sh[k], fc2W[k*32+tid], a);
    b2p[tid]=a;
  }
}

// ---- T3 (MFMA): x2 = relu(x1 @ fc2' + b2') bf16, BN2 stats. 128 rows/block ----
__global__ __launch_bounds__(256) void fc2_mfma(const unsigned short* __restrict__ x1,
    const unsigned short* __restrict__ Bt2, const float* __restrict__ b2p,
    unsigned short* __restrict__ x2, float* __restrict__ bnsum2, int M)
{
  __shared__ unsigned short xt[128*136];   // stride 136 hw (272B, 16B-aligned)
  __shared__ unsigned short wt[32*136];
  __shared__ float redS[4][32];
  __shared__ float redQ[4][32];
  int tid = threadIdx.x;
  long long base = (long long)blockIdx.x*128;
  // stage x1 rows (uint4; 128 rows x 16 chunks)
  for (int idx=tid; idx<128*16; idx+=256){
    int r = idx>>4, c = idx&15;
    uint4 u = make_uint4(0,0,0,0);
    if (base + r < M) u = *(const uint4*)&x1[(base+r)*128 + c*8];
    *(uint4*)&xt[r*136 + c*8] = u;
  }
  // stage weights (32 rows x 16 chunks)
  for (int idx=tid; idx<32*16; idx+=256){
    int r = idx>>4, c = idx&15;
    *(uint4*)&wt[r*136 + c*8] = *(const uint4*)&Bt2[r*128 + c*8];
  }
  __syncthreads();
  int wv = tid>>6, lane = tid&63;
  int m = lane&31, hi = lane>>5;
  f32x16 acc;
  #pragma unroll
  for (int i=0;i<16;i++) acc[i]=0.f;
  const unsigned short* ap = xt + (wv*32 + m)*136 + hi*8;
  const unsigned short* bp = wt + m*136 + hi*8;
  #pragma unroll
  for (int ks=0; ks<8; ks++){
    bf16x8 a = *(const bf16x8*)(ap + ks*16);
    bf16x8 b = *(const bf16x8*)(bp + ks*16);
    acc = __builtin_amdgcn_mfma_f32_32x32x16_bf16(a, b, acc, 0, 0, 0);
  }
  int col = m;
  float bias = b2p[col];
  float s=0.f, q=0.f;
  #pragma unroll
  for (int reg=0; reg<16; reg++){
    int row = (reg&3) + 8*(reg>>2) + 4*hi;
    long long grow = base + wv*32 + row;
    float v = fmaxf(acc[reg] + bias, 0.f);
    if (grow < M) x2[grow*32 + col] = f2b(v);
    s += v; q += v*v;     // zero-padded rows contribute 0 after relu(0+bias)? no: bias!=0
  }
  // NOTE: padded rows would pollute stats via relu(bias); mask them:
  // (only last block has padding; recompute s,q with mask)
  if (base + 128 > M){
    s = 0.f; q = 0.f;
    #pragma unroll
    for (int reg=0; reg<16; reg++){
      int row = (reg&3) + 8*(reg>>2) + 4*hi;
      long long grow = base + wv*32 + row;
      float v = fmaxf(acc[reg] + bias, 0.f);
      if (grow < M){ s += v; q += v*v; }
    }
  }
  s += __shfl_xor(s, 32);
  q += __shfl_xor(q, 32);
  if (hi == 0){ redS[wv][col] = s; redQ[wv][col] = q; }
  __syncthreads();
  if (tid < 32){
    float a = redS[0][tid]+redS[1][tid]+redS[2][tid]+redS[3][tid];
    float b = redQ[0][tid]+redQ[1][tid]+redQ[2][tid]+redQ[3][tid];
    atomicAdd(&bnsum2[tid], a);
    atomicAdd(&bnsum2[32+tid], b);
  }
}

// ---- T4: fold BN2 into fc3 ----
__global__ void bn2_fold(const float* __restrict__ bnsum2,
    const float* __restrict__ gamma2, const float* __restrict__ beta2,
    const float* __restrict__ fc3W, const float* __restrict__ fc3b,
    float* __restrict__ w3p, float invB)
{
  __shared__ float sh3[32];
  int tid = threadIdx.x;
  if (tid<32){
    float mu  = bnsum2[tid]*invB;
    float var = bnsum2[32+tid]*invB - mu*mu;
    float s   = gamma2[tid] * rsqrtf(var + 1e-5f);
    float shv = beta2[tid] - mu*s;
    float w   = fc3W[tid];
    w3p[tid]  = s*w;
    sh3[tid]  = shv*w;
  }
  __syncthreads();
  if (tid==0){
    float a = fc3b[0];
    for (int j=0;j<32;j++) a += sh3[j];
    w3p[32] = a;
  }
}

// ---- T5: out = x2 @ w3' + b3' (fp32 out) ----
__global__ __launch_bounds__(256) void fc3_kernel(const unsigned short* __restrict__ x2,
    const float* __restrict__ w3p, float* __restrict__ out)
{
  __shared__ float wl[34];
  int tid = threadIdx.x;
  if (tid<33) wl[tid]=w3p[tid];
  __syncthreads();
  long long row = (long long)blockIdx.x*32 + (tid>>3);
  int j0 = (tid&7)*4;
  uint2 u = *(const uint2*)(x2 + row*32 + j0);
  float a = b2f((unsigned short)(u.x&0xffffu))*wl[j0]
          + b2f((unsigned short)(u.x>>16))   *wl[j0+1]
          + b2f((unsigned short)(u.y&0xffffu))*wl[j0+2]
          + b2f((unsigned short)(u.y>>16))   *wl[j0+3];
  a += __shfl_xor(a,1);
  a += __shfl_xor(a,2);
  a += __shfl_xor(a,4);
  if ((tid&7)==0) out[row] = a + wl[32];
}

extern "C" void kernel_launch(void* const* d_in, const int* in_sizes, int n_in,
                              void* d_out, int out_size, void* d_ws, size_t ws_size,
                              hipStream_t stream)
{
  (void)in_sizes; (void)n_in; (void)out_size; (void)ws_size;
  const float* customer_x = (const float*)d_in[0];
  const float* product_x  = (const float*)d_in[1];
  const float* pcW = (const float*)d_in[2];
  const float* pcB = (const float*)d_in[3];
  const float* ppW = (const float*)d_in[4];
  const float* ppB = (const float*)d_in[5];
  const float* att_src_r  = (const float*)d_in[6];
  const float* att_dst_r  = (const float*)d_in[7];
  const float* att_src_rb = (const float*)d_in[8];
  const float* att_dst_rb = (const float*)d_in[9];
  // d_in[10..12] dead (semantic softmax over 1 metapath == 1)
  const float* color_emb = (const float*)d_in[13];
  const float* size_emb  = (const float*)d_in[14];
  const float* group_emb = (const float*)d_in[15];
  const float* fc1W = (const float*)d_in[16];
  const float* fc1b = (const float*)d_in[17];
  const float* fc2W = (const float*)d_in[18];
  const float* fc2b = (const float*)d_in[19];
  const float* fc3W = (const float*)d_in[20];
  const float* fc3b = (const float*)d_in[21];
  const float* bn1g = (const float*)d_in[22];
  const float* bn1b = (const float*)d_in[23];
  const float* bn2g = (const float*)d_in[24];
  const float* bn2b = (const float*)d_in[25];
  const int* edge_src  = (const int*)d_in[26];
  const int* edge_dst  = (const int*)d_in[27];
  const int* label_src = (const int*)d_in[28];
  const int* label_dst = (const int*)d_in[29];
  const int* size_idx  = (const int*)d_in[30];
  const int* color_idx = (const int*)d_in[31];
  const int* group_idx = (const int*)d_in[32];

  char* ws = (char*)d_ws;
  size_t off = 0;
  auto alloc = [&](size_t bytes)->char* {
    char* p = ws + off;
    off += (bytes + 255) & ~(size_t)255;
    return p;
  };
  // ~236 MB peak (< 256 MiB hard limit)
  unsigned short* H_c  = (unsigned short*)alloc((size_t)NCC*256*2);   // H_c -> out_c -> x1
  unsigned short* H_p  = (unsigned short*)alloc((size_t)NPRR*256*2);  // H_p -> Y_p
  unsigned short* out_p= (unsigned short*)alloc((size_t)NPRR*256*2);  // out_p -> Y_c
  float* s_cr     = (float*)alloc((size_t)NCC*8*4);     // x2b aliases after aggs
  float* s_crb    = (float*)alloc((size_t)NCC*8*4);
  float* s_pr     = (float*)alloc((size_t)NPRR*8*4);
  float* s_prb    = (float*)alloc((size_t)NPRR*8*4);
  int* rowptr_r   = (int*)alloc((size_t)(NPRR+1)*4);
  int* rowptr_rb  = (int*)alloc((size_t)(NCC+1)*4);
  int* srcidx_r   = (int*)alloc((size_t)NEE*4);
  int* srcidx_rb  = (int*)alloc((size_t)NEE*4);
  int* cnts       = (int*)alloc((size_t)(NCC+NPRR)*2*4);
  int* cnt_c      = cnts;
  int* cnt_p      = cnts + NCC;
  int* cnt_c2     = cnts + NCC + NPRR;
  int* cnt_p2     = cnts + NCC + NPRR + NCC;
  int* bsum_c     = (int*)alloc(256*4);
  int* bsum_p     = (int*)alloc(256*4);
  unsigned short* BtC = (unsigned short*)alloc(128*256*2);
  unsigned short* BtP = (unsigned short*)alloc(128*256*2);
  float* Ts     = (float*)alloc(30*128*4);
  float* Tc     = (float*)alloc(1000*128*4);
  float* Tg     = (float*)alloc(50*128*4);
  float* wa_c   = (float*)alloc(272*4);
  float* wa_p   = (float*)alloc(272*4);
  float* bnsum1 = (float*)alloc(256*4);
  float* bnsum2 = (float*)alloc(64*4);
  unsigned short* Bt2 = (unsigned short*)alloc(32*128*2);
  float* b2p    = (float*)alloc(32*4);
  float* w3p    = (float*)alloc(34*4);
  unsigned short* out_c = H_c;                   // H_c dead after agg_r
  unsigned short* Y_p   = H_p;                   // H_p dead after agg_rb
  unsigned short* Y_c   = out_p;                 // out_p dead after gemmY_p
  unsigned short* x1b   = H_c;                   // out_c dead after gemmY_c
  unsigned short* x2b   = (unsigned short*)s_cr; // scores dead after aggs

  hipMemsetAsync(bnsum1, 0, 1280, stream);       // bnsum1+bnsum2 contiguous
  hipMemsetAsync(cnts, 0, (size_t)(NCC+NPRR)*2*4, stream);

  // prep: WA (scores), fc1 restructure tables/weights
  wa_prep2<<<1,256,0,stream>>>(pcW, pcB, att_src_r, att_dst_rb,
                               ppW, ppB, att_dst_r, att_src_rb, wa_c, wa_p);
  prep_fc1<<<(203776+255)/256,256,0,stream>>>(fc1W, fc1b, size_emb, color_emb, group_emb,
      BtC, BtP, Ts, Tc, Tg);

  // proj + fused scores
  proj_kernel<<<2048,256,0,stream>>>(customer_x, pcW, pcB, wa_c, H_c, s_cr, s_crb, NCC);
  proj_kernel<<<2048,256,0,stream>>>(product_x,  ppW, ppB, wa_p, H_p, s_pr, s_prb, NPRR);

  // CSR build (both relations)
  const int eg = (NEE+255)/256;
  const int BP = (NPRR+1023)/1024;   // 98
  const int BC = (NCC +1023)/1024;   // 196
  hist2<<<eg,256,0,stream>>>(edge_src, edge_dst, cnt_c, cnt_p, NEE);
  scan_phase1<<<BP,256,0,stream>>>(cnt_p, bsum_p, NPRR);
  scan_phase2<<<1,256,0,stream>>>(bsum_p, BP, rowptr_r, NPRR);
  scan_phase3<<<BP,256,0,stream>>>(cnt_p, bsum_p, rowptr_r, NPRR);
  scan_phase1<<<BC,256,0,stream>>>(cnt_c, bsum_c, NCC);
  scan_phase2<<<1,256,0,stream>>>(bsum_c, BC, rowptr_rb, NCC);
  scan_phase3<<<BC,256,0,stream>>>(cnt_c, bsum_c, rowptr_rb, NCC);
  place2<<<eg,256,0,stream>>>(edge_src, edge_dst, rowptr_r, rowptr_rb,
      cnt_p2, cnt_c2, srcidx_r, srcidx_rb, NEE);

  // single-pass gather aggregation
  agg_kernel<<<(NPRR+3)/4,256,0,stream>>>(rowptr_r,  srcidx_r,  s_cr,  s_pr,  H_c, out_p, NPRR);
  agg_kernel<<<(NCC +3)/4,256,0,stream>>>(rowptr_rb, srcidx_rb, s_prb, s_crb, H_p, out_c, NCC);

  // restructured fc1: dense GEMMs (streaming) + grid-stride gather-add
  gemmY<<<NPRR/32,256,0,stream>>>(out_p, BtP, Y_p, NPRR);
  gemmY<<<NCC/32,256,0,stream>>>(out_c, BtC, Y_c, NCC);
  gather_fc1<<<2048,256,0,stream>>>(Y_c, Y_p, Ts, Tc, Tg,
      label_src, label_dst, size_idx, color_idx, group_idx, x1b, bnsum1, NBB/16);

  bn1_fold<<<1,256,0,stream>>>(bnsum1, bn1g, bn1b, fc2W, fc2b, Bt2, b2p, 1.0f/NBB);
  fc2_mfma<<<(NBB+127)/128,256,0,stream>>>(x1b, Bt2, b2p, x2b, bnsum2, NBB);
  bn2_fold<<<1,64,0,stream>>>(bnsum2, bn2g, bn2b, fc3W, fc3b, w3p, 1.0f/NBB);
  fc3_kernel<<<NBB/32,256,0,stream>>>(x2b, w3p, (float*)d_out);
}

// Round 17
// 628.072 us; speedup vs baseline: 1.5470x; 1.1046x over previous
//
#include <hip/hip_runtime.h>

#define NCC 200000
#define NPRR 100000
#define NEE 500000
#define NBB 200000

typedef __attribute__((ext_vector_type(8))) short bf16x8;
typedef __attribute__((ext_vector_type(16))) float f32x16;

__device__ __forceinline__ float b2f(unsigned short u){ return __uint_as_float(((unsigned)u)<<16); }
__device__ __forceinline__ unsigned short f2b(float f){
  unsigned x = __float_as_uint(f);
  return (unsigned short)((x + 0x7fffu + ((x>>16)&1u)) >> 16);
}
// async global->LDS DMA, 16B/lane; LDS dest = uniform base + lane*16 (HW)
__device__ __forceinline__ void gl2lds16(const void* g, void* l){
  __builtin_amdgcn_global_load_lds(
      (const __attribute__((address_space(1))) unsigned int*)g,
      (__attribute__((address_space(3))) unsigned int*)l, 16, 0, 0);
}

// ---- WA prep (both node types in one launch): WA[set][k][h] ----
__global__ __launch_bounds__(256) void wa_prep2(
    const float* __restrict__ Wc, const float* __restrict__ bc,
    const float* __restrict__ attAc, const float* __restrict__ attBc,
    const float* __restrict__ Wp, const float* __restrict__ bp,
    const float* __restrict__ attAp, const float* __restrict__ attBp,
    float* __restrict__ WAc, float* __restrict__ WAp)
{
  int tid = threadIdx.x;
  for (int task = tid; task < 4*17*8; task += 256) {
    int grp = task / 136, rem = task % 136;
    int k = rem >> 3, h = rem & 7;
    const float* att = (grp==0)?attAc:(grp==1)?attBc:(grp==2)?attAp:attBp;
    const float* W   = (grp<2)?Wc:Wp;
    const float* bias= (grp<2)?bc:bp;
    const float* row = (k < 16) ? (W + k*256) : bias;
    float acc = 0.f;
    for (int d = 0; d < 32; d++) acc = fmaf(row[h*32+d], att[h*32+d], acc);
    if (grp<2) WAc[(grp&1)*136 + rem] = acc;
    else       WAp[(grp&1)*136 + rem] = acc;
  }
}

// ---- prep for MFMA proj: Wt[n][k]=bf16(W[k][n]) (256x16); WAt[n][k] (32x16, cols>=16 zero) ----
__global__ __launch_bounds__(256) void prep_proj(
    const float* __restrict__ Wc, const float* __restrict__ Wp,
    const float* __restrict__ WAc, const float* __restrict__ WAp,
    unsigned short* __restrict__ WtC, unsigned short* __restrict__ WtP,
    unsigned short* __restrict__ WAtC, unsigned short* __restrict__ WAtP)
{
  int idx = blockIdx.x*256 + threadIdx.x;
  if (idx < 4096){ int n=idx>>4, k=idx&15; WtC[idx]=f2b(Wc[k*256+n]); }
  else if (idx < 8192){ int t=idx-4096; int n=t>>4, k=t&15; WtP[t]=f2b(Wp[k*256+n]); }
  else if (idx < 8704){ int t=idx-8192; int n=t>>4, k=t&15;
    WAtC[t] = (n<16)? f2b(WAc[(n>>3)*136 + k*8 + (n&7)]) : (unsigned short)0; }
  else if (idx < 9216){ int t=idx-8704; int n=t>>4, k=t&15;
    WAtP[t] = (n<16)? f2b(WAp[(n>>3)*136 + k*8 + (n&7)]) : (unsigned short)0; }
}

// ---- prep for restructured fc1: Bt_c/Bt_p (W1 halves, transposed bf16) + emb tables ----
__global__ __launch_bounds__(256) void prep_fc1(const float* __restrict__ fc1W,
    const float* __restrict__ fc1b,
    const float* __restrict__ size_emb, const float* __restrict__ color_emb,
    const float* __restrict__ group_emb,
    unsigned short* __restrict__ BtC, unsigned short* __restrict__ BtP,
    float* __restrict__ Ts, float* __restrict__ Tc, float* __restrict__ Tg)
{
  int idx = blockIdx.x*256 + threadIdx.x;
  if (idx < 32768){
    int n = idx>>8, k = idx&255;
    BtC[idx] = f2b(fc1W[k*128 + n]);
  } else if (idx < 65536){
    int t = idx - 32768;
    int n = t>>8, k = t&255;
    BtP[t] = f2b(fc1W[(256+k)*128 + n]);
  } else if (idx < 65536 + 30*128){
    int t = idx - 65536;
    int s = t>>7, j = t&127;
    float a = fc1b[j];
    #pragma unroll
    for (int c=0;c<4;c++) a = fmaf(size_emb[s*4+c], fc1W[(512+c)*128+j], a);
    Ts[t] = a;
  } else if (idx < 65536 + 30*128 + 1000*128){
    int t = idx - 65536 - 30*128;
    int col = t>>7, j = t&127;
    float a = 0.f;
    #pragma unroll
    for (int c=0;c<8;c++) a = fmaf(color_emb[col*8+c], fc1W[(516+c)*128+j], a);
    Tc[t] = a;
  } else if (idx < 65536 + 30*128 + 1000*128 + 50*128){
    int t = idx - 65536 - 30*128 - 1000*128;
    int g = t>>7, j = t&127;
    float a = 0.f;
    #pragma unroll
    for (int c=0;c<4;c++) a = fmaf(group_emb[g*4+c], fc1W[(524+c)*128+j], a);
    Tg[t] = a;
  }
}

// ---- proj via MFMA (K=16 -> one mfma per 32x32 tile), barrier-free main loop ----
// H[n][256] bf16 + scores sA/sB fused (extra MFMA with WAt); N % 32 == 0
__global__ __launch_bounds__(256) void proj_mfma(const float* __restrict__ X,
    const unsigned short* __restrict__ Wt, const unsigned short* __restrict__ WAt,
    const float* __restrict__ WA,
    unsigned short* __restrict__ H, float* __restrict__ sA, float* __restrict__ sB,
    int N, int nt)
{
  __shared__ unsigned short wt[4608];   // [0,4096): Wt 256x16; [4096,4608): WAt 32x16
  __shared__ float biasS[16];
  int tid = threadIdx.x;
  for (int i=tid; i<512; i+=256) ((uint4*)wt)[i] = ((const uint4*)Wt)[i];
  for (int i=tid; i<64;  i+=256) ((uint4*)(wt+4096))[i] = ((const uint4*)WAt)[i];
  if (tid < 16) biasS[tid] = WA[(tid>>3)*136 + 128 + (tid&7)];
  __syncthreads();
  int wv = tid>>6, lane = tid&63, m = lane&31, hi = lane>>5;
  for (int t = blockIdx.x; t < nt; t += gridDim.x){
    int node = t*32 + m;
    bf16x8 a;
    {
      const float4* xr = (const float4*)(X + (long long)node*16 + hi*8);
      float4 f0 = xr[0], f1 = xr[1];
      unsigned short av[8] = {f2b(f0.x),f2b(f0.y),f2b(f0.z),f2b(f0.w),
                              f2b(f1.x),f2b(f1.y),f2b(f1.z),f2b(f1.w)};
      a = *(bf16x8*)av;
    }
    #pragma unroll
    for (int s=0;s<2;s++){
      int c0 = wv*64 + s*32;
      bf16x8 b = *(const bf16x8*)(wt + (c0+m)*16 + hi*8);
      f32x16 acc;
      #pragma unroll
      for (int i=0;i<16;i++) acc[i]=0.f;
      acc = __builtin_amdgcn_mfma_f32_32x32x16_bf16(a, b, acc, 0, 0, 0);
      #pragma unroll
      for (int reg=0; reg<16; reg++){
        int row = (reg&3) + 8*(reg>>2) + 4*hi;
        H[(long long)(t*32+row)*256 + c0 + m] = f2b(acc[reg]);
      }
    }
    if (wv == 0){
      bf16x8 b = *(const bf16x8*)(wt + 4096 + m*16 + hi*8);
      f32x16 acc;
      #pragma unroll
      for (int i=0;i<16;i++) acc[i]=0.f;
      acc = __builtin_amdgcn_mfma_f32_32x32x16_bf16(a, b, acc, 0, 0, 0);
      if (m < 16){
        float bias = biasS[m];
        float* dst = (m < 8) ? sA : sB;
        int h = m & 7;
        #pragma unroll
        for (int reg=0; reg<16; reg++){
          int row = (reg&3) + 8*(reg>>2) + 4*hi;
          dst[(long long)(t*32+row)*8 + h] = acc[reg] + bias;
        }
      }
    }
  }
}

// ---- fused degree histogram for both relations ----
__global__ __launch_bounds__(256) void hist2(const int* __restrict__ src, const int* __restrict__ dst,
    int* __restrict__ cnt_c, int* __restrict__ cnt_p, int E)
{
  int e = blockIdx.x*256 + threadIdx.x;
  if (e >= E) return;
  atomicAdd(&cnt_p[dst[e]], 1);
  atomicAdd(&cnt_c[src[e]], 1);
}

// ---- hierarchical exclusive scan ----
__global__ __launch_bounds__(256) void scan_phase1(const int* __restrict__ cnt, int* __restrict__ bsum, int N)
{
  __shared__ int red[256];
  int tid = threadIdx.x;
  int base = blockIdx.x*1024 + tid*4;
  int s = 0;
  #pragma unroll
  for (int k=0;k<4;k++){ int i=base+k; if (i<N) s += cnt[i]; }
  red[tid] = s;
  __syncthreads();
  for (int off=128; off>0; off>>=1){ if (tid<off) red[tid]+=red[tid+off]; __syncthreads(); }
  if (tid==0) bsum[blockIdx.x] = red[0];
}

__global__ __launch_bounds__(256) void scan_phase2(int* __restrict__ bsum, int B,
    int* __restrict__ rowptr, int N)
{
  __shared__ int ts[256];
  int tid = threadIdx.x;
  int v = (tid<B) ? bsum[tid] : 0;
  ts[tid] = v;
  __syncthreads();
  for (int off=1; off<256; off<<=1){
    int t = (tid>=off) ? ts[tid-off] : 0;
    __syncthreads();
    ts[tid] += t;
    __syncthreads();
  }
  if (tid < B) bsum[tid] = ts[tid] - v;
  if (tid == B-1) rowptr[N] = ts[tid];
}

__global__ __launch_bounds__(256) void scan_phase3(const int* __restrict__ cnt,
    const int* __restrict__ bsum, int* __restrict__ rowptr, int N)
{
  __shared__ int ts[256];
  int tid = threadIdx.x;
  int base = blockIdx.x*1024 + tid*4;
  int v[4]; int s = 0;
  #pragma unroll
  for (int k=0;k<4;k++){ int i=base+k; v[k] = (i<N) ? cnt[i] : 0; s += v[k]; }
  ts[tid] = s;
  __syncthreads();
  for (int off=1; off<256; off<<=1){
    int t = (tid>=off) ? ts[tid-off] : 0;
    __syncthreads();
    ts[tid] += t;
    __syncthreads();
  }
  int run = bsum[blockIdx.x] + ts[tid] - s;
  #pragma unroll
  for (int k=0;k<4;k++){ int i=base+k; if (i<N){ rowptr[i]=run; run += v[k]; } }
}

// ---- fused placement for both relations (uses pre-zeroed cnt2 buffers) ----
__global__ __launch_bounds__(256) void place2(const int* __restrict__ src, const int* __restrict__ dst,
    const int* __restrict__ rp_r, const int* __restrict__ rp_rb,
    int* __restrict__ cnt_p, int* __restrict__ cnt_c,
    int* __restrict__ si_r, int* __restrict__ si_rb, int E)
{
  int e = blockIdx.x*256 + threadIdx.x;
  if (e >= E) return;
  int s = src[e], d = dst[e];
  si_r [rp_r [d] + atomicAdd(&cnt_p[d], 1)] = s;
  si_rb[rp_rb[s] + atomicAdd(&cnt_c[s], 1)] = d;
}

// ---- aggregation v2: lanes split (side, colgroup); uint4 row loads; single pass ----
__global__ __launch_bounds__(256) void agg_kernel(
    const int* __restrict__ rowptr, const int* __restrict__ srcidx,
    const float* __restrict__ sSrc, const float* __restrict__ sDst,
    const unsigned short* __restrict__ H, unsigned short* __restrict__ out, int N)
{
  int wv = threadIdx.x >> 6, lane = threadIdx.x & 63;
  int n = blockIdx.x*4 + wv;
  if (n >= N) return;
  int e0 = rowptr[n], e1 = rowptr[n+1];
  int j = lane & 31;
  int side = lane >> 5;
  int h = j >> 2;
  float sdh = sDst[(long long)n*8 + h];
  float a0=0,a1=0,a2=0,a3=0,a4=0,a5=0,a6=0,a7=0, da=0.f;
  float b0=0,b1=0,b2=0,b3=0,b4=0,b5=0,b6=0,b7=0, db=0.f;
  int e = e0 + side;
  for (; e + 2 < e1; e += 4){
    int sA = srcidx[e], sB = srcidx[e+2];
    float lA = sSrc[(long long)sA*8 + h] + sdh;
    float lB = sSrc[(long long)sB*8 + h] + sdh;
    uint4 uA = *(const uint4*)&H[(long long)sA*256 + j*8];
    uint4 uB = *(const uint4*)&H[(long long)sB*256 + j*8];
    float wA = __expf(lA > 0.f ? lA : 0.2f*lA);
    float wB = __expf(lB > 0.f ? lB : 0.2f*lB);
    da += wA; db += wB;
    a0 = fmaf(wA, b2f((unsigned short)(uA.x&0xffffu)), a0);
    a1 = fmaf(wA, b2f((unsigned short)(uA.x>>16)),     a1);
    a2 = fmaf(wA, b2f((unsigned short)(uA.y&0xffffu)), a2);
    a3 = fmaf(wA, b2f((unsigned short)(uA.y>>16)),     a3);
    a4 = fmaf(wA, b2f((unsigned short)(uA.z&0xffffu)), a4);
    a5 = fmaf(wA, b2f((unsigned short)(uA.z>>16)),     a5);
    a6 = fmaf(wA, b2f((unsigned short)(uA.w&0xffffu)), a6);
    a7 = fmaf(wA, b2f((unsigned short)(uA.w>>16)),     a7);
    b0 = fmaf(wB, b2f((unsigned short)(uB.x&0xffffu)), b0);
    b1 = fmaf(wB, b2f((unsigned short)(uB.x>>16)),     b1);
    b2 = fmaf(wB, b2f((unsigned short)(uB.y&0xffffu)), b2);
    b3 = fmaf(wB, b2f((unsigned short)(uB.y>>16)),     b3);
    b4 = fmaf(wB, b2f((unsigned short)(uB.z&0xffffu)), b4);
    b5 = fmaf(wB, b2f((unsigned short)(uB.z>>16)),     b5);
    b6 = fmaf(wB, b2f((unsigned short)(uB.w&0xffffu)), b6);
    b7 = fmaf(wB, b2f((unsigned short)(uB.w>>16)),     b7);
  }
  for (; e < e1; e += 2){
    int s = srcidx[e];
    float l = sSrc[(long long)s*8 + h] + sdh;
    uint4 u = *(const uint4*)&H[(long long)s*256 + j*8];
    float w = __expf(l > 0.f ? l : 0.2f*l);
    da += w;
    a0 = fmaf(w, b2f((unsigned short)(u.x&0xffffu)), a0);
    a1 = fmaf(w, b2f((unsigned short)(u.x>>16)),     a1);
    a2 = fmaf(w, b2f((unsigned short)(u.y&0xffffu)), a2);
    a3 = fmaf(w, b2f((unsigned short)(u.y>>16)),     a3);
    a4 = fmaf(w, b2f((unsigned short)(u.z&0xffffu)), a4);
    a5 = fmaf(w, b2f((unsigned short)(u.z>>16)),     a5);
    a6 = fmaf(w, b2f((unsigned short)(u.w&0xffffu)), a6);
    a7 = fmaf(w, b2f((unsigned short)(u.w>>16)),     a7);
  }
  a0+=b0; a1+=b1; a2+=b2; a3+=b3; a4+=b4; a5+=b5; a6+=b6; a7+=b7;
  da += db;
  a0 += __shfl_xor(a0,32); a1 += __shfl_xor(a1,32);
  a2 += __shfl_xor(a2,32); a3 += __shfl_xor(a3,32);
  a4 += __shfl_xor(a4,32); a5 += __shfl_xor(a5,32);
  a6 += __shfl_xor(a6,32); a7 += __shfl_xor(a7,32);
  da += __shfl_xor(da,32);
  float inv = 1.f/(da + 1e-16f);
  if (side == 0){
    uint4 o;
    o.x = (unsigned)f2b(fmaxf(a0*inv,0.f)) | ((unsigned)f2b(fmaxf(a1*inv,0.f))<<16);
    o.y = (unsigned)f2b(fmaxf(a2*inv,0.f)) | ((unsigned)f2b(fmaxf(a3*inv,0.f))<<16);
    o.z = (unsigned)f2b(fmaxf(a4*inv,0.f)) | ((unsigned)f2b(fmaxf(a5*inv,0.f))<<16);
    o.w = (unsigned)f2b(fmaxf(a6*inv,0.f)) | ((unsigned)f2b(fmaxf(a7*inv,0.f))<<16);
    *(uint4*)&out[(long long)n*256 + j*8] = o;
  }
}

// ---- dense streaming GEMM: Y[M][128] = A[M][256] @ Bt^T (both bf16, fp32 acc) ----
__global__ __launch_bounds__(256) void gemmY(const unsigned short* __restrict__ A,
    const unsigned short* __restrict__ Bt, unsigned short* __restrict__ Y, int M)
{
  __shared__ unsigned short feat[32*264];
  int tid = threadIdx.x;
  int wv = tid>>6, lane = tid&63;
  long long base = (long long)blockIdx.x*32;
  #pragma unroll
  for (int i=0;i<8;i++){
    int r = wv*8 + i;
    if (lane < 32) gl2lds16(A + (base+r)*256 + lane*8, &feat[r*264]);
  }
  __syncthreads();
  int m = lane&31, hi = lane>>5;
  f32x16 acc;
  #pragma unroll
  for (int i=0;i<16;i++) acc[i]=0.f;
  const unsigned short* ap  = feat + m*264 + hi*8;
  const unsigned short* btp = Bt + (wv*32 + m)*256 + hi*8;
  #pragma unroll 4
  for (int ks=0; ks<16; ks++){
    bf16x8 a = *(const bf16x8*)(ap + ks*16);
    bf16x8 b = *(const bf16x8*)(btp + ks*16);
    acc = __builtin_amdgcn_mfma_f32_32x32x16_bf16(a, b, acc, 0, 0, 0);
  }
  int col = wv*32 + m;
  #pragma unroll
  for (int reg=0; reg<16; reg++){
    int row = (reg&3) + 8*(reg>>2) + 4*hi;
    Y[(base+row)*128 + col] = f2b(acc[reg]);
  }
}

// ---- gather + sum + relu + BN1 stats (grid-stride, register stat accumulation) ----
__global__ __launch_bounds__(256) void gather_fc1(
    const unsigned short* __restrict__ Yc, const unsigned short* __restrict__ Yp,
    const float* __restrict__ Ts, const float* __restrict__ Tc, const float* __restrict__ Tg,
    const int* __restrict__ lsrc, const int* __restrict__ ldst,
    const int* __restrict__ sidx, const int* __restrict__ cidx, const int* __restrict__ gidx,
    unsigned short* __restrict__ x1, float* __restrict__ bnsum, int ntiles)
{
  __shared__ float redS[16][128];
  __shared__ float redQ[16][128];
  int tid = threadIdx.x;
  int rl = tid>>4, g = tid&15;
  float sacc[8] = {0,0,0,0,0,0,0,0};
  float qacc[8] = {0,0,0,0,0,0,0,0};
  for (int t = blockIdx.x; t < ntiles; t += gridDim.x){
    long long row = (long long)t*16 + rl;
    int ls = lsrc[row], ld = ldst[row], si = sidx[row], ci = cidx[row], gi = gidx[row];
    uint4 uc = *(const uint4*)&Yc[(long long)ls*128 + g*8];
    uint4 up = *(const uint4*)&Yp[(long long)ld*128 + g*8];
    float4 t0 = *(const float4*)&Ts[si*128 + g*8];
    float4 t1 = *(const float4*)&Ts[si*128 + g*8 + 4];
    float4 c0 = *(const float4*)&Tc[ci*128 + g*8];
    float4 c1 = *(const float4*)&Tc[ci*128 + g*8 + 4];
    float4 g0 = *(const float4*)&Tg[gi*128 + g*8];
    float4 g1 = *(const float4*)&Tg[gi*128 + g*8 + 4];
    unsigned ucs[4] = {uc.x,uc.y,uc.z,uc.w};
    unsigned ups[4] = {up.x,up.y,up.z,up.w};
    float tb[8] = {t0.x+c0.x+g0.x, t0.y+c0.y+g0.y, t0.z+c0.z+g0.z, t0.w+c0.w+g0.w,
                   t1.x+c1.x+g1.x, t1.y+c1.y+g1.y, t1.z+c1.z+g1.z, t1.w+c1.w+g1.w};
    unsigned short ov[8];
    #pragma unroll
    for (int p=0;p<4;p++){
      float vl = b2f((unsigned short)(ucs[p]&0xffffu)) + b2f((unsigned short)(ups[p]&0xffffu)) + tb[p*2];
      float vh = b2f((unsigned short)(ucs[p]>>16))     + b2f((unsigned short)(ups[p]>>16))     + tb[p*2+1];
      vl = fmaxf(vl, 0.f); vh = fmaxf(vh, 0.f);
      ov[p*2] = f2b(vl); ov[p*2+1] = f2b(vh);
      sacc[p*2]   += vl; qacc[p*2]   += vl*vl;
      sacc[p*2+1] += vh; qacc[p*2+1] += vh*vh;
    }
    *(uint4*)&x1[row*128 + g*8] = *(uint4*)ov;
  }
  #pragma unroll
  for (int j=0;j<8;j++){ redS[rl][g*8+j]=sacc[j]; redQ[rl][g*8+j]=qacc[j]; }
  __syncthreads();
  if (tid < 128){
    float s=0.f, q=0.f;
    #pragma unroll
    for (int r=0;r<16;r++){ s += redS[r][tid]; q += redQ[r][tid]; }
    atomicAdd(&bnsum[tid], s);
    atomicAdd(&bnsum[128+tid], q);
  }
}

// ---- T2: fold BN1 into fc2, emit bf16 transposed weights Bt2[32][128] + fp32 bias ----
__global__ void bn1_fold(const float* __restrict__ bnsum,
    const float* __restrict__ gamma, const float* __restrict__ beta,
    const float* __restrict__ fc2W, const float* __restrict__ fc2b,
    unsigned short* __restrict__ Bt2, float* __restrict__ b2p, float invB)
{
  __shared__ float sc[128], sh[128];
  int tid = threadIdx.x;
  if (tid<128){
    float mu  = bnsum[tid]*invB;
    float var = bnsum[128+tid]*invB - mu*mu;
    float s = gamma[tid] * rsqrtf(var + 1e-5f);
    sc[tid]=s; sh[tid]= beta[tid] - mu*s;
  }
  __syncthreads();
  for (int idx=tid; idx<32*128; idx+=256){
    int n = idx>>7, k = idx&127;
    Bt2[idx] = f2b(sc[k]*fc2W[k*32+n]);
  }
  if (tid<32){
    float a = fc2b[tid];
    for (int k=0;k<128;k++) a = fmaf(sh[k], fc2W[k*32+tid], a);
    b2p[tid]=a;
  }
}

// ---- T3 (MFMA): x2 = relu(x1 @ fc2' + b2') bf16, BN2 stats. 128 rows/block ----
__global__ __launch_bounds__(256) void fc2_mfma(const unsigned short* __restrict__ x1,
    const unsigned short* __restrict__ Bt2, const float* __restrict__ b2p,
    unsigned short* __restrict__ x2, float* __restrict__ bnsum2, int M)
{
  __shared__ unsigned short xt[128*136];
  __shared__ unsigned short wt[32*136];
  __shared__ float redS[4][32];
  __shared__ float redQ[4][32];
  int tid = threadIdx.x;
  long long base = (long long)blockIdx.x*128;
  for (int idx=tid; idx<128*16; idx+=256){
    int r = idx>>4, c = idx&15;
    uint4 u = make_uint4(0,0,0,0);
    if (base + r < M) u = *(const uint4*)&x1[(base+r)*128 + c*8];
    *(uint4*)&xt[r*136 + c*8] = u;
  }
  for (int idx=tid; idx<32*16; idx+=256){
    int r = idx>>4, c = idx&15;
    *(uint4*)&wt[r*136 + c*8] = *(const uint4*)&Bt2[r*128 + c*8];
  }
  __syncthreads();
  int wv = tid>>6, lane = tid&63;
  int m = lane&31, hi = lane>>5;
  f32x16 acc;
  #pragma unroll
  for (int i=0;i<16;i++) acc[i]=0.f;
  const unsigned short* ap = xt + (wv*32 + m)*136 + hi*8;
  const unsigned short* bp = wt + m*136 + hi*8;
  #pragma unroll
  for (int ks=0; ks<8; ks++){
    bf16x8 a = *(const bf16x8*)(ap + ks*16);
    bf16x8 b = *(const bf16x8*)(bp + ks*16);
    acc = __builtin_amdgcn_mfma_f32_32x32x16_bf16(a, b, acc, 0, 0, 0);
  }
  int col = m;
  float bias = b2p[col];
  float s=0.f, q=0.f;
  #pragma unroll
  for (int reg=0; reg<16; reg++){
    int row = (reg&3) + 8*(reg>>2) + 4*hi;
    long long grow = base + wv*32 + row;
    float v = fmaxf(acc[reg] + bias, 0.f);
    if (grow < M) x2[grow*32 + col] = f2b(v);
    s += v; q += v*v;
  }
  if (base + 128 > M){
    s = 0.f; q = 0.f;
    #pragma unroll
    for (int reg=0; reg<16; reg++){
      int row = (reg&3) + 8*(reg>>2) + 4*hi;
      long long grow = base + wv*32 + row;
      float v = fmaxf(acc[reg] + bias, 0.f);
      if (grow < M){ s += v; q += v*v; }
    }
  }
  s += __shfl_xor(s, 32);
  q += __shfl_xor(q, 32);
  if (hi == 0){ redS[wv][col] = s; redQ[wv][col] = q; }
  __syncthreads();
  if (tid < 32){
    float a = redS[0][tid]+redS[1][tid]+redS[2][tid]+redS[3][tid];
    float b = redQ[0][tid]+redQ[1][tid]+redQ[2][tid]+redQ[3][tid];
    atomicAdd(&bnsum2[tid], a);
    atomicAdd(&bnsum2[32+tid], b);
  }
}

// ---- T4: fold BN2 into fc3 ----
__global__ void bn2_fold(const float* __restrict__ bnsum2,
    const float* __restrict__ gamma2, const float* __restrict__ beta2,
    const float* __restrict__ fc3W, const float* __restrict__ fc3b,
    float* __restrict__ w3p, float invB)
{
  __shared__ float sh3[32];
  int tid = threadIdx.x;
  if (tid<32){
    float mu  = bnsum2[tid]*invB;
    float var = bnsum2[32+tid]*invB - mu*mu;
    float s   = gamma2[tid] * rsqrtf(var + 1e-5f);
    float shv = beta2[tid] - mu*s;
    float w   = fc3W[tid];
    w3p[tid]  = s*w;
    sh3[tid]  = shv*w;
  }
  __syncthreads();
  if (tid==0){
    float a = fc3b[0];
    for (int j=0;j<32;j++) a += sh3[j];
    w3p[32] = a;
  }
}

// ---- T5: out = x2 @ w3' + b3' (fp32 out) ----
__global__ __launch_bounds__(256) void fc3_kernel(const unsigned short* __restrict__ x2,
    const float* __restrict__ w3p, float* __restrict__ out)
{
  __shared__ float wl[34];
  int tid = threadIdx.x;
  if (tid<33) wl[tid]=w3p[tid];
  __syncthreads();
  long long row = (long long)blockIdx.x*32 + (tid>>3);
  int j0 = (tid&7)*4;
  uint2 u = *(const uint2*)(x2 + row*32 + j0);
  float a = b2f((unsigned short)(u.x&0xffffu))*wl[j0]
          + b2f((unsigned short)(u.x>>16))   *wl[j0+1]
          + b2f((unsigned short)(u.y&0xffffu))*wl[j0+2]
          + b2f((unsigned short)(u.y>>16))   *wl[j0+3];
  a += __shfl_xor(a,1);
  a += __shfl_xor(a,2);
  a += __shfl_xor(a,4);
  if ((tid&7)==0) out[row] = a + wl[32];
}

extern "C" void kernel_launch(void* const* d_in, const int* in_sizes, int n_in,
                              void* d_out, int out_size, void* d_ws, size_t ws_size,
                              hipStream_t stream)
{
  (void)in_sizes; (void)n_in; (void)out_size; (void)ws_size;
  const float* customer_x = (const float*)d_in[0];
  const float* product_x  = (const float*)d_in[1];
  const float* pcW = (const float*)d_in[2];
  const float* pcB = (const float*)d_in[3];
  const float* ppW = (const float*)d_in[4];
  const float* ppB = (const float*)d_in[5];
  const float* att_src_r  = (const float*)d_in[6];
  const float* att_dst_r  = (const float*)d_in[7];
  const float* att_src_rb = (const float*)d_in[8];
  const float* att_dst_rb = (const float*)d_in[9];
  // d_in[10..12] dead (semantic softmax over 1 metapath == 1)
  const float* color_emb = (const float*)d_in[13];
  const float* size_emb  = (const float*)d_in[14];
  const float* group_emb = (const float*)d_in[15];
  const float* fc1W = (const float*)d_in[16];
  const float* fc1b = (const float*)d_in[17];
  const float* fc2W = (const float*)d_in[18];
  const float* fc2b = (const float*)d_in[19];
  const float* fc3W = (const float*)d_in[20];
  const float* fc3b = (const float*)d_in[21];
  const float* bn1g = (const float*)d_in[22];
  const float* bn1b = (const float*)d_in[23];
  const float* bn2g = (const float*)d_in[24];
  const float* bn2b = (const float*)d_in[25];
  const int* edge_src  = (const int*)d_in[26];
  const int* edge_dst  = (const int*)d_in[27];
  const int* label_src = (const int*)d_in[28];
  const int* label_dst = (const int*)d_in[29];
  const int* size_idx  = (const int*)d_in[30];
  const int* color_idx = (const int*)d_in[31];
  const int* group_idx = (const int*)d_in[32];

  char* ws = (char*)d_ws;
  size_t off = 0;
  auto alloc = [&](size_t bytes)->char* {
    char* p = ws + off;
    off += (bytes + 255) & ~(size_t)255;
    return p;
  };
  // ~236 MB peak (< 256 MiB hard limit)
  unsigned short* H_c  = (unsigned short*)alloc((size_t)NCC*256*2);   // H_c -> out_c -> x1
  unsigned short* H_p  = (unsigned short*)alloc((size_t)NPRR*256*2);  // H_p -> Y_p
  unsigned short* out_p= (unsigned short*)alloc((size_t)NPRR*256*2);  // out_p -> Y_c
  float* s_cr     = (float*)alloc((size_t)NCC*8*4);     // x2b aliases after aggs
  float* s_crb    = (float*)alloc((size_t)NCC*8*4);
  float* s_pr     = (float*)alloc((size_t)NPRR*8*4);
  float* s_prb    = (float*)alloc((size_t)NPRR*8*4);
  int* rowptr_r   = (int*)alloc((size_t)(NPRR+1)*4);
  int* rowptr_rb  = (int*)alloc((size_t)(NCC+1)*4);
  int* srcidx_r   = (int*)alloc((size_t)NEE*4);
  int* srcidx_rb  = (int*)alloc((size_t)NEE*4);
  int* cnts       = (int*)alloc((size_t)(NCC+NPRR)*2*4);
  int* cnt_c      = cnts;
  int* cnt_p      = cnts + NCC;
  int* cnt_c2     = cnts + NCC + NPRR;
  int* cnt_p2     = cnts + NCC + NPRR + NCC;
  int* bsum_c     = (int*)alloc(256*4);
  int* bsum_p     = (int*)alloc(256*4);
  unsigned short* BtC = (unsigned short*)alloc(128*256*2);
  unsigned short* BtP = (unsigned short*)alloc(128*256*2);
  float* Ts     = (float*)alloc(30*128*4);
  float* Tc     = (float*)alloc(1000*128*4);
  float* Tg     = (float*)alloc(50*128*4);
  float* wa_c   = (float*)alloc(272*4);
  float* wa_p   = (float*)alloc(272*4);
  unsigned short* WtC  = (unsigned short*)alloc(256*16*2);
  unsigned short* WtP  = (unsigned short*)alloc(256*16*2);
  unsigned short* WAtC = (unsigned short*)alloc(32*16*2);
  unsigned short* WAtP = (unsigned short*)alloc(32*16*2);
  float* bnsum1 = (float*)alloc(256*4);
  float* bnsum2 = (float*)alloc(64*4);
  unsigned short* Bt2 = (unsigned short*)alloc(32*128*2);
  float* b2p    = (float*)alloc(32*4);
  float* w3p    = (float*)alloc(34*4);
  unsigned short* out_c = H_c;                   // H_c dead after agg_r
  unsigned short* Y_p   = H_p;                   // H_p dead after agg_rb
  unsigned short* Y_c   = out_p;                 // out_p dead after gemmY_p
  unsigned short* x1b   = H_c;                   // out_c dead after gemmY_c
  unsigned short* x2b   = (unsigned short*)s_cr; // scores dead after aggs

  hipMemsetAsync(bnsum1, 0, 1280, stream);       // bnsum1+bnsum2 contiguous
  hipMemsetAsync(cnts, 0, (size_t)(NCC+NPRR)*2*4, stream);

  // prep: WA (scores), proj MFMA weights, fc1 restructure tables/weights
  wa_prep2<<<1,256,0,stream>>>(pcW, pcB, att_src_r, att_dst_rb,
                               ppW, ppB, att_dst_r, att_src_rb, wa_c, wa_p);
  prep_proj<<<36,256,0,stream>>>(pcW, ppW, wa_c, wa_p, WtC, WtP, WAtC, WAtP);
  prep_fc1<<<(203776+255)/256,256,0,stream>>>(fc1W, fc1b, size_emb, color_emb, group_emb,
      BtC, BtP, Ts, Tc, Tg);

  // proj via MFMA (barrier-free), scores fused
  proj_mfma<<<2048,256,0,stream>>>(customer_x, WtC, WAtC, wa_c, H_c, s_cr, s_crb, NCC, NCC/32);
  proj_mfma<<<2048,256,0,stream>>>(product_x,  WtP, WAtP, wa_p, H_p, s_pr, s_prb, NPRR, NPRR/32);

  // CSR build (both relations)
  const int eg = (NEE+255)/256;
  const int BP = (NPRR+1023)/1024;   // 98
  const int BC = (NCC +1023)/1024;   // 196
  hist2<<<eg,256,0,stream>>>(edge_src, edge_dst, cnt_c, cnt_p, NEE);
  scan_phase1<<<BP,256,0,stream>>>(cnt_p, bsum_p, NPRR);
  scan_phase2<<<1,256,0,stream>>>(bsum_p, BP, rowptr_r, NPRR);
  scan_phase3<<<BP,256,0,stream>>>(cnt_p, bsum_p, rowptr_r, NPRR);
  scan_phase1<<<BC,256,0,stream>>>(cnt_c, bsum_c, NCC);
  scan_phase2<<<1,256,0,stream>>>(bsum_c, BC, rowptr_rb, NCC);
  scan_phase3<<<BC,256,0,stream>>>(cnt_c, bsum_c, rowptr_rb, NCC);
  place2<<<eg,256,0,stream>>>(edge_src, edge_dst, rowptr_r, rowptr_rb,
      cnt_p2, cnt_c2, srcidx_r, srcidx_rb, NEE);

  // single-pass gather aggregation
  agg_kernel<<<(NPRR+3)/4,256,0,stream>>>(rowptr_r,  srcidx_r,  s_cr,  s_pr,  H_c, out_p, NPRR);
  agg_kernel<<<(NCC +3)/4,256,0,stream>>>(rowptr_rb, srcidx_rb, s_prb, s_crb, H_p, out_c, NCC);

  // restructured fc1: dense GEMMs (streaming) + grid-stride gather-add
  gemmY<<<NPRR/32,256,0,stream>>>(out_p, BtP, Y_p, NPRR);
  gemmY<<<NCC/32,256,0,stream>>>(out_c, BtC, Y_c, NCC);
  gather_fc1<<<2048,256,0,stream>>>(Y_c, Y_p, Ts, Tc, Tg,
      label_src, label_dst, size_idx, color_idx, group_idx, x1b, bnsum1, NBB/16);

  bn1_fold<<<1,256,0,stream>>>(bnsum1, bn1g, bn1b, fc2W, fc2b, Bt2, b2p, 1.0f/NBB);
  fc2_mfma<<<(NBB+127)/128,256,0,stream>>>(x1b, Bt2, b2p, x2b, bnsum2, NBB);
  bn2_fold<<<1,64,0,stream>>>(bnsum2, bn2g, bn2b, fc3W, fc3b, w3p, 1.0f/NBB);
  fc3_kernel<<<NBB/32,256,0,stream>>>(x2b, w3p, (float*)d_out);
}

// Round 18
// 612.164 us; speedup vs baseline: 1.5873x; 1.0260x over previous
//
#include <hip/hip_runtime.h>

#define NCC 200000
#define NPRR 100000
#define NEE 500000
#define NBB 200000

typedef __attribute__((ext_vector_type(8))) short bf16x8;
typedef __attribute__((ext_vector_type(16))) float f32x16;

__device__ __forceinline__ float b2f(unsigned short u){ return __uint_as_float(((unsigned)u)<<16); }
__device__ __forceinline__ unsigned short f2b(float f){
  unsigned x = __float_as_uint(f);
  return (unsigned short)((x + 0x7fffu + ((x>>16)&1u)) >> 16);
}

// ---- WA prep (both node types in one launch): WA[set][k][h] ----
__global__ __launch_bounds__(256) void wa_prep2(
    const float* __restrict__ Wc, const float* __restrict__ bc,
    const float* __restrict__ attAc, const float* __restrict__ attBc,
    const float* __restrict__ Wp, const float* __restrict__ bp,
    const float* __restrict__ attAp, const float* __restrict__ attBp,
    float* __restrict__ WAc, float* __restrict__ WAp)
{
  int tid = threadIdx.x;
  for (int task = tid; task < 4*17*8; task += 256) {
    int grp = task / 136, rem = task % 136;
    int k = rem >> 3, h = rem & 7;
    const float* att = (grp==0)?attAc:(grp==1)?attBc:(grp==2)?attAp:attBp;
    const float* W   = (grp<2)?Wc:Wp;
    const float* bias= (grp<2)?bc:bp;
    const float* row = (k < 16) ? (W + k*256) : bias;
    float acc = 0.f;
    for (int d = 0; d < 32; d++) acc = fmaf(row[h*32+d], att[h*32+d], acc);
    if (grp<2) WAc[(grp&1)*136 + rem] = acc;
    else       WAp[(grp&1)*136 + rem] = acc;
  }
}

// ---- prep for MFMA proj: Wt[n][k]=bf16(W[k][n]) (256x16); WAt[n][k] (32x16, cols>=16 zero) ----
__global__ __launch_bounds__(256) void prep_proj(
    const float* __restrict__ Wc, const float* __restrict__ Wp,
    const float* __restrict__ WAc, const float* __restrict__ WAp,
    unsigned short* __restrict__ WtC, unsigned short* __restrict__ WtP,
    unsigned short* __restrict__ WAtC, unsigned short* __restrict__ WAtP)
{
  int idx = blockIdx.x*256 + threadIdx.x;
  if (idx < 4096){ int n=idx>>4, k=idx&15; WtC[idx]=f2b(Wc[k*256+n]); }
  else if (idx < 8192){ int t=idx-4096; int n=t>>4, k=t&15; WtP[t]=f2b(Wp[k*256+n]); }
  else if (idx < 8704){ int t=idx-8192; int n=t>>4, k=t&15;
    WAtC[t] = (n<16)? f2b(WAc[(n>>3)*136 + k*8 + (n&7)]) : (unsigned short)0; }
  else if (idx < 9216){ int t=idx-8704; int n=t>>4, k=t&15;
    WAtP[t] = (n<16)? f2b(WAp[(n>>3)*136 + k*8 + (n&7)]) : (unsigned short)0; }
}

// ---- prep for restructured fc1: Bt_c/Bt_p (W1 halves, transposed bf16) + emb tables ----
__global__ __launch_bounds__(256) void prep_fc1(const float* __restrict__ fc1W,
    const float* __restrict__ fc1b,
    const float* __restrict__ size_emb, const float* __restrict__ color_emb,
    const float* __restrict__ group_emb,
    unsigned short* __restrict__ BtC, unsigned short* __restrict__ BtP,
    float* __restrict__ Ts, float* __restrict__ Tc, float* __restrict__ Tg)
{
  int idx = blockIdx.x*256 + threadIdx.x;
  if (idx < 32768){
    int n = idx>>8, k = idx&255;
    BtC[idx] = f2b(fc1W[k*128 + n]);
  } else if (idx < 65536){
    int t = idx - 32768;
    int n = t>>8, k = t&255;
    BtP[t] = f2b(fc1W[(256+k)*128 + n]);
  } else if (idx < 65536 + 30*128){
    int t = idx - 65536;
    int s = t>>7, j = t&127;
    float a = fc1b[j];
    #pragma unroll
    for (int c=0;c<4;c++) a = fmaf(size_emb[s*4+c], fc1W[(512+c)*128+j], a);
    Ts[t] = a;
  } else if (idx < 65536 + 30*128 + 1000*128){
    int t = idx - 65536 - 30*128;
    int col = t>>7, j = t&127;
    float a = 0.f;
    #pragma unroll
    for (int c=0;c<8;c++) a = fmaf(color_emb[col*8+c], fc1W[(516+c)*128+j], a);
    Tc[t] = a;
  } else if (idx < 65536 + 30*128 + 1000*128 + 50*128){
    int t = idx - 65536 - 30*128 - 1000*128;
    int g = t>>7, j = t&127;
    float a = 0.f;
    #pragma unroll
    for (int c=0;c<4;c++) a = fmaf(group_emb[g*4+c], fc1W[(524+c)*128+j], a);
    Tg[t] = a;
  }
}

// ---- proj via MFMA (K=16 -> one mfma per 32x32 tile), barrier-free main loop ----
__global__ __launch_bounds__(256) void proj_mfma(const float* __restrict__ X,
    const unsigned short* __restrict__ Wt, const unsigned short* __restrict__ WAt,
    const float* __restrict__ WA,
    unsigned short* __restrict__ H, float* __restrict__ sA, float* __restrict__ sB,
    int N, int nt)
{
  __shared__ unsigned short wt[4608];
  __shared__ float biasS[16];
  int tid = threadIdx.x;
  for (int i=tid; i<512; i+=256) ((uint4*)wt)[i] = ((const uint4*)Wt)[i];
  for (int i=tid; i<64;  i+=256) ((uint4*)(wt+4096))[i] = ((const uint4*)WAt)[i];
  if (tid < 16) biasS[tid] = WA[(tid>>3)*136 + 128 + (tid&7)];
  __syncthreads();
  int wv = tid>>6, lane = tid&63, m = lane&31, hi = lane>>5;
  for (int t = blockIdx.x; t < nt; t += gridDim.x){
    int node = t*32 + m;
    bf16x8 a;
    {
      const float4* xr = (const float4*)(X + (long long)node*16 + hi*8);
      float4 f0 = xr[0], f1 = xr[1];
      unsigned short av[8] = {f2b(f0.x),f2b(f0.y),f2b(f0.z),f2b(f0.w),
                              f2b(f1.x),f2b(f1.y),f2b(f1.z),f2b(f1.w)};
      a = *(bf16x8*)av;
    }
    #pragma unroll
    for (int s=0;s<2;s++){
      int c0 = wv*64 + s*32;
      bf16x8 b = *(const bf16x8*)(wt + (c0+m)*16 + hi*8);
      f32x16 acc;
      #pragma unroll
      for (int i=0;i<16;i++) acc[i]=0.f;
      acc = __builtin_amdgcn_mfma_f32_32x32x16_bf16(a, b, acc, 0, 0, 0);
      #pragma unroll
      for (int reg=0; reg<16; reg++){
        int row = (reg&3) + 8*(reg>>2) + 4*hi;
        H[(long long)(t*32+row)*256 + c0 + m] = f2b(acc[reg]);
      }
    }
    if (wv == 0){
      bf16x8 b = *(const bf16x8*)(wt + 4096 + m*16 + hi*8);
      f32x16 acc;
      #pragma unroll
      for (int i=0;i<16;i++) acc[i]=0.f;
      acc = __builtin_amdgcn_mfma_f32_32x32x16_bf16(a, b, acc, 0, 0, 0);
      if (m < 16){
        float bias = biasS[m];
        float* dst = (m < 8) ? sA : sB;
        int h = m & 7;
        #pragma unroll
        for (int reg=0; reg<16; reg++){
          int row = (reg&3) + 8*(reg>>2) + 4*hi;
          dst[(long long)(t*32+row)*8 + h] = acc[reg] + bias;
        }
      }
    }
  }
}

// ---- fused degree histogram for both relations ----
__global__ __launch_bounds__(256) void hist2(const int* __restrict__ src, const int* __restrict__ dst,
    int* __restrict__ cnt_c, int* __restrict__ cnt_p, int E)
{
  int e = blockIdx.x*256 + threadIdx.x;
  if (e >= E) return;
  atomicAdd(&cnt_p[dst[e]], 1);
  atomicAdd(&cnt_c[src[e]], 1);
}

// ---- hierarchical exclusive scan ----
__global__ __launch_bounds__(256) void scan_phase1(const int* __restrict__ cnt, int* __restrict__ bsum, int N)
{
  __shared__ int red[256];
  int tid = threadIdx.x;
  int base = blockIdx.x*1024 + tid*4;
  int s = 0;
  #pragma unroll
  for (int k=0;k<4;k++){ int i=base+k; if (i<N) s += cnt[i]; }
  red[tid] = s;
  __syncthreads();
  for (int off=128; off>0; off>>=1){ if (tid<off) red[tid]+=red[tid+off]; __syncthreads(); }
  if (tid==0) bsum[blockIdx.x] = red[0];
}

__global__ __launch_bounds__(256) void scan_phase2(int* __restrict__ bsum, int B,
    int* __restrict__ rowptr, int N)
{
  __shared__ int ts[256];
  int tid = threadIdx.x;
  int v = (tid<B) ? bsum[tid] : 0;
  ts[tid] = v;
  __syncthreads();
  for (int off=1; off<256; off<<=1){
    int t = (tid>=off) ? ts[tid-off] : 0;
    __syncthreads();
    ts[tid] += t;
    __syncthreads();
  }
  if (tid < B) bsum[tid] = ts[tid] - v;
  if (tid == B-1) rowptr[N] = ts[tid];
}

__global__ __launch_bounds__(256) void scan_phase3(const int* __restrict__ cnt,
    const int* __restrict__ bsum, int* __restrict__ rowptr, int N)
{
  __shared__ int ts[256];
  int tid = threadIdx.x;
  int base = blockIdx.x*1024 + tid*4;
  int v[4]; int s = 0;
  #pragma unroll
  for (int k=0;k<4;k++){ int i=base+k; v[k] = (i<N) ? cnt[i] : 0; s += v[k]; }
  ts[tid] = s;
  __syncthreads();
  for (int off=1; off<256; off<<=1){
    int t = (tid>=off) ? ts[tid-off] : 0;
    __syncthreads();
    ts[tid] += t;
    __syncthreads();
  }
  int run = bsum[blockIdx.x] + ts[tid] - s;
  #pragma unroll
  for (int k=0;k<4;k++){ int i=base+k; if (i<N){ rowptr[i]=run; run += v[k]; } }
}

// ---- fused placement for both relations (uses pre-zeroed cnt2 buffers) ----
__global__ __launch_bounds__(256) void place2(const int* __restrict__ src, const int* __restrict__ dst,
    const int* __restrict__ rp_r, const int* __restrict__ rp_rb,
    int* __restrict__ cnt_p, int* __restrict__ cnt_c,
    int* __restrict__ si_r, int* __restrict__ si_rb, int E)
{
  int e = blockIdx.x*256 + threadIdx.x;
  if (e >= E) return;
  int s = src[e], d = dst[e];
  si_r [rp_r [d] + atomicAdd(&cnt_p[d], 1)] = s;
  si_rb[rp_rb[s] + atomicAdd(&cnt_c[s], 1)] = d;
}

// ---- FUSED agg + gemmY: block = 32-node tile; aggregate into LDS, MFMA epilogue -> Y ----
// wave handles 8 nodes serially (lanes: side=lane>>5 over edges, j=lane&31 over col-pairs);
// then 16-step MFMA per wave computes Y[32x32 tile] = relu(out)@Bt^T. out never hits HBM.
__global__ __launch_bounds__(256) void agg_gemm(
    const int* __restrict__ rowptr, const int* __restrict__ srcidx,
    const float* __restrict__ sSrc, const float* __restrict__ sDst,
    const unsigned short* __restrict__ H, const unsigned short* __restrict__ Bt,
    unsigned short* __restrict__ Y)
{
  __shared__ unsigned short feat[32*264];
  int tid = threadIdx.x;
  int wv = tid>>6, lane = tid&63;
  int j = lane & 31, side = lane >> 5, h = j >> 2;
  long long base = (long long)blockIdx.x*32;
  #pragma unroll 1
  for (int i=0;i<8;i++){
    int r = wv*8 + i;
    long long n = base + r;
    int e0 = rowptr[n], e1 = rowptr[n+1];
    float sdh = sDst[n*8 + h];
    float a0=0,a1=0,a2=0,a3=0,a4=0,a5=0,a6=0,a7=0, da=0.f;
    float b0=0,b1=0,b2=0,b3=0,b4=0,b5=0,b6=0,b7=0, db=0.f;
    int e = e0 + side;
    for (; e + 2 < e1; e += 4){
      int sA = srcidx[e], sB = srcidx[e+2];
      float lA = sSrc[(long long)sA*8 + h] + sdh;
      float lB = sSrc[(long long)sB*8 + h] + sdh;
      uint4 uA = *(const uint4*)&H[(long long)sA*256 + j*8];
      uint4 uB = *(const uint4*)&H[(long long)sB*256 + j*8];
      float wA = __expf(lA > 0.f ? lA : 0.2f*lA);
      float wB = __expf(lB > 0.f ? lB : 0.2f*lB);
      da += wA; db += wB;
      a0 = fmaf(wA, b2f((unsigned short)(uA.x&0xffffu)), a0);
      a1 = fmaf(wA, b2f((unsigned short)(uA.x>>16)),     a1);
      a2 = fmaf(wA, b2f((unsigned short)(uA.y&0xffffu)), a2);
      a3 = fmaf(wA, b2f((unsigned short)(uA.y>>16)),     a3);
      a4 = fmaf(wA, b2f((unsigned short)(uA.z&0xffffu)), a4);
      a5 = fmaf(wA, b2f((unsigned short)(uA.z>>16)),     a5);
      a6 = fmaf(wA, b2f((unsigned short)(uA.w&0xffffu)), a6);
      a7 = fmaf(wA, b2f((unsigned short)(uA.w>>16)),     a7);
      b0 = fmaf(wB, b2f((unsigned short)(uB.x&0xffffu)), b0);
      b1 = fmaf(wB, b2f((unsigned short)(uB.x>>16)),     b1);
      b2 = fmaf(wB, b2f((unsigned short)(uB.y&0xffffu)), b2);
      b3 = fmaf(wB, b2f((unsigned short)(uB.y>>16)),     b3);
      b4 = fmaf(wB, b2f((unsigned short)(uB.z&0xffffu)), b4);
      b5 = fmaf(wB, b2f((unsigned short)(uB.z>>16)),     b5);
      b6 = fmaf(wB, b2f((unsigned short)(uB.w&0xffffu)), b6);
      b7 = fmaf(wB, b2f((unsigned short)(uB.w>>16)),     b7);
    }
    for (; e < e1; e += 2){
      int s = srcidx[e];
      float l = sSrc[(long long)s*8 + h] + sdh;
      uint4 u = *(const uint4*)&H[(long long)s*256 + j*8];
      float w = __expf(l > 0.f ? l : 0.2f*l);
      da += w;
      a0 = fmaf(w, b2f((unsigned short)(u.x&0xffffu)), a0);
      a1 = fmaf(w, b2f((unsigned short)(u.x>>16)),     a1);
      a2 = fmaf(w, b2f((unsigned short)(u.y&0xffffu)), a2);
      a3 = fmaf(w, b2f((unsigned short)(u.y>>16)),     a3);
      a4 = fmaf(w, b2f((unsigned short)(u.z&0xffffu)), a4);
      a5 = fmaf(w, b2f((unsigned short)(u.z>>16)),     a5);
      a6 = fmaf(w, b2f((unsigned short)(u.w&0xffffu)), a6);
      a7 = fmaf(w, b2f((unsigned short)(u.w>>16)),     a7);
    }
    a0+=b0; a1+=b1; a2+=b2; a3+=b3; a4+=b4; a5+=b5; a6+=b6; a7+=b7;
    da += db;
    a0 += __shfl_xor(a0,32); a1 += __shfl_xor(a1,32);
    a2 += __shfl_xor(a2,32); a3 += __shfl_xor(a3,32);
    a4 += __shfl_xor(a4,32); a5 += __shfl_xor(a5,32);
    a6 += __shfl_xor(a6,32); a7 += __shfl_xor(a7,32);
    da += __shfl_xor(da,32);
    float inv = 1.f/(da + 1e-16f);
    if (side == 0){
      unsigned short ov[8];
      ov[0]=f2b(fmaxf(a0*inv,0.f)); ov[1]=f2b(fmaxf(a1*inv,0.f));
      ov[2]=f2b(fmaxf(a2*inv,0.f)); ov[3]=f2b(fmaxf(a3*inv,0.f));
      ov[4]=f2b(fmaxf(a4*inv,0.f)); ov[5]=f2b(fmaxf(a5*inv,0.f));
      ov[6]=f2b(fmaxf(a6*inv,0.f)); ov[7]=f2b(fmaxf(a7*inv,0.f));
      *(uint4*)&feat[r*264 + j*8] = *(uint4*)ov;
    }
  }
  __syncthreads();
  // gemm epilogue: Y[32 rows][128 cols] = feat @ Bt^T
  int m = lane&31, hi = lane>>5;
  f32x16 acc;
  #pragma unroll
  for (int i=0;i<16;i++) acc[i]=0.f;
  const unsigned short* ap  = feat + m*264 + hi*8;
  const unsigned short* btp = Bt + (wv*32 + m)*256 + hi*8;
  #pragma unroll 4
  for (int ks=0; ks<16; ks++){
    bf16x8 a = *(const bf16x8*)(ap + ks*16);
    bf16x8 b = *(const bf16x8*)(btp + ks*16);
    acc = __builtin_amdgcn_mfma_f32_32x32x16_bf16(a, b, acc, 0, 0, 0);
  }
  int col = wv*32 + m;
  #pragma unroll
  for (int reg=0; reg<16; reg++){
    int row = (reg&3) + 8*(reg>>2) + 4*hi;
    Y[(base+row)*128 + col] = f2b(acc[reg]);
  }
}

// ---- gather + sum + relu + BN1 stats (grid-stride, register stat accumulation) ----
__global__ __launch_bounds__(256) void gather_fc1(
    const unsigned short* __restrict__ Yc, const unsigned short* __restrict__ Yp,
    const float* __restrict__ Ts, const float* __restrict__ Tc, const float* __restrict__ Tg,
    const int* __restrict__ lsrc, const int* __restrict__ ldst,
    const int* __restrict__ sidx, const int* __restrict__ cidx, const int* __restrict__ gidx,
    unsigned short* __restrict__ x1, float* __restrict__ bnsum, int ntiles)
{
  __shared__ float redS[16][128];
  __shared__ float redQ[16][128];
  int tid = threadIdx.x;
  int rl = tid>>4, g = tid&15;
  float sacc[8] = {0,0,0,0,0,0,0,0};
  float qacc[8] = {0,0,0,0,0,0,0,0};
  for (int t = blockIdx.x; t < ntiles; t += gridDim.x){
    long long row = (long long)t*16 + rl;
    int ls = lsrc[row], ld = ldst[row], si = sidx[row], ci = cidx[row], gi = gidx[row];
    uint4 uc = *(const uint4*)&Yc[(long long)ls*128 + g*8];
    uint4 up = *(const uint4*)&Yp[(long long)ld*128 + g*8];
    float4 t0 = *(const float4*)&Ts[si*128 + g*8];
    float4 t1 = *(const float4*)&Ts[si*128 + g*8 + 4];
    float4 c0 = *(const float4*)&Tc[ci*128 + g*8];
    float4 c1 = *(const float4*)&Tc[ci*128 + g*8 + 4];
    float4 g0 = *(const float4*)&Tg[gi*128 + g*8];
    float4 g1 = *(const float4*)&Tg[gi*128 + g*8 + 4];
    unsigned ucs[4] = {uc.x,uc.y,uc.z,uc.w};
    unsigned ups[4] = {up.x,up.y,up.z,up.w};
    float tb[8] = {t0.x+c0.x+g0.x, t0.y+c0.y+g0.y, t0.z+c0.z+g0.z, t0.w+c0.w+g0.w,
                   t1.x+c1.x+g1.x, t1.y+c1.y+g1.y, t1.z+c1.z+g1.z, t1.w+c1.w+g1.w};
    unsigned short ov[8];
    #pragma unroll
    for (int p=0;p<4;p++){
      float vl = b2f((unsigned short)(ucs[p]&0xffffu)) + b2f((unsigned short)(ups[p]&0xffffu)) + tb[p*2];
      float vh = b2f((unsigned short)(ucs[p]>>16))     + b2f((unsigned short)(ups[p]>>16))     + tb[p*2+1];
      vl = fmaxf(vl, 0.f); vh = fmaxf(vh, 0.f);
      ov[p*2] = f2b(vl); ov[p*2+1] = f2b(vh);
      sacc[p*2]   += vl; qacc[p*2]   += vl*vl;
      sacc[p*2+1] += vh; qacc[p*2+1] += vh*vh;
    }
    *(uint4*)&x1[row*128 + g*8] = *(uint4*)ov;
  }
  #pragma unroll
  for (int j=0;j<8;j++){ redS[rl][g*8+j]=sacc[j]; redQ[rl][g*8+j]=qacc[j]; }
  __syncthreads();
  if (tid < 128){
    float s=0.f, q=0.f;
    #pragma unroll
    for (int r=0;r<16;r++){ s += redS[r][tid]; q += redQ[r][tid]; }
    atomicAdd(&bnsum[tid], s);
    atomicAdd(&bnsum[128+tid], q);
  }
}

// ---- T2: fold BN1 into fc2, emit bf16 transposed weights Bt2[32][128] + fp32 bias ----
__global__ void bn1_fold(const float* __restrict__ bnsum,
    const float* __restrict__ gamma, const float* __restrict__ beta,
    const float* __restrict__ fc2W, const float* __restrict__ fc2b,
    unsigned short* __restrict__ Bt2, float* __restrict__ b2p, float invB)
{
  __shared__ float sc[128], sh[128];
  int tid = threadIdx.x;
  if (tid<128){
    float mu  = bnsum[tid]*invB;
    float var = bnsum[128+tid]*invB - mu*mu;
    float s = gamma[tid] * rsqrtf(var + 1e-5f);
    sc[tid]=s; sh[tid]= beta[tid] - mu*s;
  }
  __syncthreads();
  for (int idx=tid; idx<32*128; idx+=256){
    int n = idx>>7, k = idx&127;
    Bt2[idx] = f2b(sc[k]*fc2W[k*32+n]);
  }
  if (tid<32){
    float a = fc2b[tid];
    for (int k=0;k<128;k++) a = fmaf(sh[k], fc2W[k*32+tid], a);
    b2p[tid]=a;
  }
}

// ---- T3 (MFMA): x2 = relu(x1 @ fc2' + b2') bf16, BN2 stats. 128 rows/block ----
__global__ __launch_bounds__(256) void fc2_mfma(const unsigned short* __restrict__ x1,
    const unsigned short* __restrict__ Bt2, const float* __restrict__ b2p,
    unsigned short* __restrict__ x2, float* __restrict__ bnsum2, int M)
{
  __shared__ unsigned short xt[128*136];
  __shared__ unsigned short wt[32*136];
  __shared__ float redS[4][32];
  __shared__ float redQ[4][32];
  int tid = threadIdx.x;
  long long base = (long long)blockIdx.x*128;
  for (int idx=tid; idx<128*16; idx+=256){
    int r = idx>>4, c = idx&15;
    uint4 u = make_uint4(0,0,0,0);
    if (base + r < M) u = *(const uint4*)&x1[(base+r)*128 + c*8];
    *(uint4*)&xt[r*136 + c*8] = u;
  }
  for (int idx=tid; idx<32*16; idx+=256){
    int r = idx>>4, c = idx&15;
    *(uint4*)&wt[r*136 + c*8] = *(const uint4*)&Bt2[r*128 + c*8];
  }
  __syncthreads();
  int wv = tid>>6, lane = tid&63;
  int m = lane&31, hi = lane>>5;
  f32x16 acc;
  #pragma unroll
  for (int i=0;i<16;i++) acc[i]=0.f;
  const unsigned short* ap = xt + (wv*32 + m)*136 + hi*8;
  const unsigned short* bp = wt + m*136 + hi*8;
  #pragma unroll
  for (int ks=0; ks<8; ks++){
    bf16x8 a = *(const bf16x8*)(ap + ks*16);
    bf16x8 b = *(const bf16x8*)(bp + ks*16);
    acc = __builtin_amdgcn_mfma_f32_32x32x16_bf16(a, b, acc, 0, 0, 0);
  }
  int col = m;
  float bias = b2p[col];
  float s=0.f, q=0.f;
  #pragma unroll
  for (int reg=0; reg<16; reg++){
    int row = (reg&3) + 8*(reg>>2) + 4*hi;
    long long grow = base + wv*32 + row;
    float v = fmaxf(acc[reg] + bias, 0.f);
    if (grow < M) x2[grow*32 + col] = f2b(v);
    s += v; q += v*v;
  }
  if (base + 128 > M){
    s = 0.f; q = 0.f;
    #pragma unroll
    for (int reg=0; reg<16; reg++){
      int row = (reg&3) + 8*(reg>>2) + 4*hi;
      long long grow = base + wv*32 + row;
      float v = fmaxf(acc[reg] + bias, 0.f);
      if (grow < M){ s += v; q += v*v; }
    }
  }
  s += __shfl_xor(s, 32);
  q += __shfl_xor(q, 32);
  if (hi == 0){ redS[wv][col] = s; redQ[wv][col] = q; }
  __syncthreads();
  if (tid < 32){
    float a = redS[0][tid]+redS[1][tid]+redS[2][tid]+redS[3][tid];
    float b = redQ[0][tid]+redQ[1][tid]+redQ[2][tid]+redQ[3][tid];
    atomicAdd(&bnsum2[tid], a);
    atomicAdd(&bnsum2[32+tid], b);
  }
}

// ---- T4: fold BN2 into fc3 ----
__global__ void bn2_fold(const float* __restrict__ bnsum2,
    const float* __restrict__ gamma2, const float* __restrict__ beta2,
    const float* __restrict__ fc3W, const float* __restrict__ fc3b,
    float* __restrict__ w3p, float invB)
{
  __shared__ float sh3[32];
  int tid = threadIdx.x;
  if (tid<32){
    float mu  = bnsum2[tid]*invB;
    float var = bnsum2[32+tid]*invB - mu*mu;
    float s   = gamma2[tid] * rsqrtf(var + 1e-5f);
    float shv = beta2[tid] - mu*s;
    float w   = fc3W[tid];
    w3p[tid]  = s*w;
    sh3[tid]  = shv*w;
  }
  __syncthreads();
  if (tid==0){
    float a = fc3b[0];
    for (int j=0;j<32;j++) a += sh3[j];
    w3p[32] = a;
  }
}

// ---- T5: out = x2 @ w3' + b3' (fp32 out) ----
__global__ __launch_bounds__(256) void fc3_kernel(const unsigned short* __restrict__ x2,
    const float* __restrict__ w3p, float* __restrict__ out)
{
  __shared__ float wl[34];
  int tid = threadIdx.x;
  if (tid<33) wl[tid]=w3p[tid];
  __syncthreads();
  long long row = (long long)blockIdx.x*32 + (tid>>3);
  int j0 = (tid&7)*4;
  uint2 u = *(const uint2*)(x2 + row*32 + j0);
  float a = b2f((unsigned short)(u.x&0xffffu))*wl[j0]
          + b2f((unsigned short)(u.x>>16))   *wl[j0+1]
          + b2f((unsigned short)(u.y&0xffffu))*wl[j0+2]
          + b2f((unsigned short)(u.y>>16))   *wl[j0+3];
  a += __shfl_xor(a,1);
  a += __shfl_xor(a,2);
  a += __shfl_xor(a,4);
  if ((tid&7)==0) out[row] = a + wl[32];
}

extern "C" void kernel_launch(void* const* d_in, const int* in_sizes, int n_in,
                              void* d_out, int out_size, void* d_ws, size_t ws_size,
                              hipStream_t stream)
{
  (void)in_sizes; (void)n_in; (void)out_size; (void)ws_size;
  const float* customer_x = (const float*)d_in[0];
  const float* product_x  = (const float*)d_in[1];
  const float* pcW = (const float*)d_in[2];
  const float* pcB = (const float*)d_in[3];
  const float* ppW = (const float*)d_in[4];
  const float* ppB = (const float*)d_in[5];
  const float* att_src_r  = (const float*)d_in[6];
  const float* att_dst_r  = (const float*)d_in[7];
  const float* att_src_rb = (const float*)d_in[8];
  const float* att_dst_rb = (const float*)d_in[9];
  // d_in[10..12] dead (semantic softmax over 1 metapath == 1)
  const float* color_emb = (const float*)d_in[13];
  const float* size_emb  = (const float*)d_in[14];
  const float* group_emb = (const float*)d_in[15];
  const float* fc1W = (const float*)d_in[16];
  const float* fc1b = (const float*)d_in[17];
  const float* fc2W = (const float*)d_in[18];
  const float* fc2b = (const float*)d_in[19];
  const float* fc3W = (const float*)d_in[20];
  const float* fc3b = (const float*)d_in[21];
  const float* bn1g = (const float*)d_in[22];
  const float* bn1b = (const float*)d_in[23];
  const float* bn2g = (const float*)d_in[24];
  const float* bn2b = (const float*)d_in[25];
  const int* edge_src  = (const int*)d_in[26];
  const int* edge_dst  = (const int*)d_in[27];
  const int* label_src = (const int*)d_in[28];
  const int* label_dst = (const int*)d_in[29];
  const int* size_idx  = (const int*)d_in[30];
  const int* color_idx = (const int*)d_in[31];
  const int* group_idx = (const int*)d_in[32];

  char* ws = (char*)d_ws;
  size_t off = 0;
  auto alloc = [&](size_t bytes)->char* {
    char* p = ws + off;
    off += (bytes + 255) & ~(size_t)255;
    return p;
  };
  // ~236 MB peak (< 256 MiB hard limit)
  unsigned short* H_c  = (unsigned short*)alloc((size_t)NCC*256*2);   // H_c -> Y_c
  unsigned short* H_p  = (unsigned short*)alloc((size_t)NPRR*256*2);  // H_p -> x1
  unsigned short* slab = (unsigned short*)alloc((size_t)NPRR*256*2);  // Y_p
  float* s_cr     = (float*)alloc((size_t)NCC*8*4);     // x2b aliases after aggs
  float* s_crb    = (float*)alloc((size_t)NCC*8*4);
  float* s_pr     = (float*)alloc((size_t)NPRR*8*4);
  float* s_prb    = (float*)alloc((size_t)NPRR*8*4);
  int* rowptr_r   = (int*)alloc((size_t)(NPRR+1)*4);
  int* rowptr_rb  = (int*)alloc((size_t)(NCC+1)*4);
  int* srcidx_r   = (int*)alloc((size_t)NEE*4);
  int* srcidx_rb  = (int*)alloc((size_t)NEE*4);
  int* cnts       = (int*)alloc((size_t)(NCC+NPRR)*2*4);
  int* cnt_c      = cnts;
  int* cnt_p      = cnts + NCC;
  int* cnt_c2     = cnts + NCC + NPRR;
  int* cnt_p2     = cnts + NCC + NPRR + NCC;
  int* bsum_c     = (int*)alloc(256*4);
  int* bsum_p     = (int*)alloc(256*4);
  unsigned short* BtC = (unsigned short*)alloc(128*256*2);
  unsigned short* BtP = (unsigned short*)alloc(128*256*2);
  float* Ts     = (float*)alloc(30*128*4);
  float* Tc     = (float*)alloc(1000*128*4);
  float* Tg     = (float*)alloc(50*128*4);
  float* wa_c   = (float*)alloc(272*4);
  float* wa_p   = (float*)alloc(272*4);
  unsigned short* WtC  = (unsigned short*)alloc(256*16*2);
  unsigned short* WtP  = (unsigned short*)alloc(256*16*2);
  unsigned short* WAtC = (unsigned short*)alloc(32*16*2);
  unsigned short* WAtP = (unsigned short*)alloc(32*16*2);
  float* bnsum1 = (float*)alloc(256*4);
  float* bnsum2 = (float*)alloc(64*4);
  unsigned short* Bt2 = (unsigned short*)alloc(32*128*2);
  float* b2p    = (float*)alloc(32*4);
  float* w3p    = (float*)alloc(34*4);
  unsigned short* Y_p = slab;                    // written by agg_gemm_r (reads H_c)
  unsigned short* Y_c = H_c;                     // H_c dead after agg_gemm_r
  unsigned short* x1b = H_p;                     // H_p dead after agg_gemm_rb
  unsigned short* x2b = (unsigned short*)s_cr;   // scores dead after aggs

  hipMemsetAsync(bnsum1, 0, 1280, stream);       // bnsum1+bnsum2 contiguous
  hipMemsetAsync(cnts, 0, (size_t)(NCC+NPRR)*2*4, stream);

  // prep: WA (scores), proj MFMA weights, fc1 restructure tables/weights
  wa_prep2<<<1,256,0,stream>>>(pcW, pcB, att_src_r, att_dst_rb,
                               ppW, ppB, att_dst_r, att_src_rb, wa_c, wa_p);
  prep_proj<<<36,256,0,stream>>>(pcW, ppW, wa_c, wa_p, WtC, WtP, WAtC, WAtP);
  prep_fc1<<<(203776+255)/256,256,0,stream>>>(fc1W, fc1b, size_emb, color_emb, group_emb,
      BtC, BtP, Ts, Tc, Tg);

  // proj via MFMA (barrier-free), scores fused
  proj_mfma<<<2048,256,0,stream>>>(customer_x, WtC, WAtC, wa_c, H_c, s_cr, s_crb, NCC, NCC/32);
  proj_mfma<<<2048,256,0,stream>>>(product_x,  WtP, WAtP, wa_p, H_p, s_pr, s_prb, NPRR, NPRR/32);

  // CSR build (both relations)
  const int eg = (NEE+255)/256;
  const int BP = (NPRR+1023)/1024;   // 98
  const int BC = (NCC +1023)/1024;   // 196
  hist2<<<eg,256,0,stream>>>(edge_src, edge_dst, cnt_c, cnt_p, NEE);
  scan_phase1<<<BP,256,0,stream>>>(cnt_p, bsum_p, NPRR);
  scan_phase2<<<1,256,0,stream>>>(bsum_p, BP, rowptr_r, NPRR);
  scan_phase3<<<BP,256,0,stream>>>(cnt_p, bsum_p, rowptr_r, NPRR);
  scan_phase1<<<BC,256,0,stream>>>(cnt_c, bsum_c, NCC);
  scan_phase2<<<1,256,0,stream>>>(bsum_c, BC, rowptr_rb, NCC);
  scan_phase3<<<BC,256,0,stream>>>(cnt_c, bsum_c, rowptr_rb, NCC);
  place2<<<eg,256,0,stream>>>(edge_src, edge_dst, rowptr_r, rowptr_rb,
      cnt_p2, cnt_c2, srcidx_r, srcidx_rb, NEE);

  // FUSED aggregation + fc1-half GEMM (out never materialized)
  agg_gemm<<<NPRR/32,256,0,stream>>>(rowptr_r,  srcidx_r,  s_cr,  s_pr,  H_c, BtP, Y_p);
  agg_gemm<<<NCC/32,256,0,stream>>>(rowptr_rb, srcidx_rb, s_prb, s_crb, H_p, BtC, Y_c);

  // gather-add + BN1 stats
  gather_fc1<<<2048,256,0,stream>>>(Y_c, Y_p, Ts, Tc, Tg,
      label_src, label_dst, size_idx, color_idx, group_idx, x1b, bnsum1, NBB/16);

  bn1_fold<<<1,256,0,stream>>>(bnsum1, bn1g, bn1b, fc2W, fc2b, Bt2, b2p, 1.0f/NBB);
  fc2_mfma<<<(NBB+127)/128,256,0,stream>>>(x1b, Bt2, b2p, x2b, bnsum2, NBB);
  bn2_fold<<<1,64,0,stream>>>(bnsum2, bn2g, bn2b, fc3W, fc3b, w3p, 1.0f/NBB);
  fc3_kernel<<<NBB/32,256,0,stream>>>(x2b, w3p, (float*)d_out);
}